// Round 7
// baseline (314.243 us; speedup 1.0000x reference)
//
#include <hip/hip_runtime.h>
#include <hip/hip_bf16.h>

// MemoryEfficientMultiheadAttention: chunked (block-diagonal) MHA.
// S=4096, B=4, D=1024, H=16, dk=64, CHUNK=256.
// cvt(weights, qkv->bf16) -> fused QKV GEMM (A2/B3 LDS ring, counted vmcnt(2),
// chunk-swizzled staging, LDS-staged head-major epilogue) -> flash attn
// (swapped QK^T, P-in-reg PV) -> out proj (same ring).

namespace {

constexpr int kSeq = 4096, kB = 4, kDm = 1024, kNh = 16, kDk = 64, kChk = 256;
constexpr int kMr = kSeq * kB;       // 16384 GEMM rows
constexpr float kLog2e = 1.44269504088896340736f;

typedef __attribute__((ext_vector_type(8))) short bf16x8;
typedef __attribute__((ext_vector_type(4))) short bf16x4;
typedef __attribute__((ext_vector_type(4))) float f32x4;
typedef __attribute__((ext_vector_type(8))) unsigned short u16x8;
typedef __attribute__((ext_vector_type(4))) unsigned short u16x4;

__device__ __forceinline__ unsigned short f2bf(float x) {
  union { float f; unsigned u; } v; v.f = x;
  unsigned r = v.u + 0x7fffu + ((v.u >> 16) & 1u);   // RNE
  return (unsigned short)(r >> 16);
}
// HW packed f32->bf16 (RNE), 1 VALU op for 2 elements.
__device__ __forceinline__ unsigned cvtpk(float lo, float hi) {
  unsigned r;
  asm("v_cvt_pk_bf16_f32 %0, %1, %2" : "=v"(r) : "v"(lo), "v"(hi));
  return r;
}
// XOR swizzle for 128B-row-stride LDS tiles: xor byte bits 4-6 with row&7.
__device__ __forceinline__ int swz(int bo) { return bo ^ ((bo >> 3) & 0x70); }

__device__ __forceinline__ f32x4 mfma16x16(bf16x4 a, bf16x4 b, f32x4 c) {
#if __has_builtin(__builtin_amdgcn_mfma_f32_16x16x16bf16_1k)
  return __builtin_amdgcn_mfma_f32_16x16x16bf16_1k(a, b, c, 0, 0, 0);
#else
  asm volatile("v_mfma_f32_16x16x16_bf16 %0, %1, %2, %0\n\ts_nop 4"
               : "+v"(c) : "v"(a), "v"(b));
  return c;
#endif
}

// All four 1024x1024 weights -> bf16, dst contiguous (Wq|Wk|Wv|Wo).
__global__ __launch_bounds__(256) void cvt4(const float* __restrict__ s0,
                                            const float* __restrict__ s1,
                                            const float* __restrict__ s2,
                                            const float* __restrict__ s3,
                                            unsigned short* __restrict__ dst) {
  int i = blockIdx.x * 256 + threadIdx.x;          // 0 .. 4*2^18-1
  int t = i >> 18;
  int j = i & 0x3ffff;
  const float* s = (t == 0) ? s0 : (t == 1) ? s1 : (t == 2) ? s2 : s3;
  f32x4 v = *(const f32x4*)(s + (size_t)j * 4);
  u16x4 o;
  o[0] = f2bf(v[0]); o[1] = f2bf(v[1]); o[2] = f2bf(v[2]); o[3] = f2bf(v[3]);
  *(u16x4*)(dst + (size_t)i * 4) = o;
}

// query|key|value fp32 -> bf16, three contiguous 16M-elem tensors.
__global__ __launch_bounds__(256) void cvt3(const float* __restrict__ s0,
                                            const float* __restrict__ s1,
                                            const float* __restrict__ s2,
                                            unsigned short* __restrict__ dst) {
  size_t i = (size_t)blockIdx.x * 256 + threadIdx.x;   // 3 * 2^22 chunks
  int t = (int)(i >> 22);
  size_t j = i & 0x3fffff;
  const float* s = (t == 0) ? s0 : (t == 1) ? s1 : s2;
  f32x4 v = *(const f32x4*)(s + j * 4);
  u16x4 o;
  o[0] = f2bf(v[0]); o[1] = f2bf(v[1]); o[2] = f2bf(v[2]); o[3] = f2bf(v[3]);
  *(u16x4*)(dst + i * 4) = o;
}

// Fused QKV projection: C_mat = A_mat @ W_mat^T + b_mat, mat in {q,k,v}.
// 128x128 tile, BK=32, 4 waves. A:2-slot / B:3-slot LDS ring (40KB -> 4
// blocks/CU), counted vmcnt(2), 16B-chunk XOR swizzle (source-permuted global
// addr + permuted ds_read). rbi-fastest XCD map keeps W panel L2-resident.
__global__ __launch_bounds__(256) void gemm_qkv(const unsigned short* __restrict__ qbf,
                                                const unsigned short* __restrict__ kbf,
                                                const unsigned short* __restrict__ vbf,
                                                const unsigned short* __restrict__ Wcat,
                                                const float* __restrict__ bq,
                                                const float* __restrict__ bk,
                                                const float* __restrict__ bv,
                                                unsigned short* __restrict__ dst,
                                                float sQ) {
  constexpr int K = kDm;
  __shared__ unsigned short sh[20480];   // A: 2x8KB @0; B: 3x8KB @8192; epi C 32KB @0
  const int tid = (int)threadIdx.x;
  const int l = tid & 63;
  const int wbase = tid & ~63;
  const int bid = (int)blockIdx.x;
  const int rbi = ((bid & 7) << 4) | ((bid >> 3) & 15);   // 0..127
  const int cbi = bid >> 7;                               // 0..23
  const int rb = rbi * 128;
  const int mat = cbi >> 3, ccol = (cbi & 7) * 128;
  const unsigned short* A = (mat == 0) ? qbf : (mat == 1) ? kbf : vbf;
  const float* bp = (mat == 0) ? bq : (mat == 1) ? bk : bv;
  const float scale = (mat == 0) ? sQ : 1.0f;
  unsigned short* out = dst + (size_t)mat * kMr * kDm;
  const int wr = ((tid >> 7) & 1) * 64;
  const int wc = ((tid >> 6) & 1) * 64;
  const int l15 = l & 15, l4 = l >> 4;

  // Staging: thread stages chunks ch=i*256+tid (i=0,1); rr=i*64+(tid>>2),
  // c4=tid&3. Source permutation c4 -> c4^(rr&3) (rr&3 identical for both i).
  const int rr0 = tid >> 2;
  const int c4p = (tid & 3) ^ (rr0 & 3);
  const unsigned short* gA0 = A + (size_t)(rb + rr0) * K + c4p * 8;
  const unsigned short* gA1 = gA0 + (size_t)64 * K;
  const unsigned short* gB0 = Wcat + (size_t)(cbi * 128 + rr0) * K + c4p * 8;
  const unsigned short* gB1 = gB0 + (size_t)64 * K;
  const int rchk = (l4 ^ (l15 & 3)) * 8;   // ds_read side of the permutation

  f32x4 acc[4][4] = {};

  auto stageA = [&](int slot, int kt) {
    unsigned short* d = sh + slot * 4096;
    __builtin_amdgcn_global_load_lds(
        (const __attribute__((address_space(1))) unsigned int*)(gA0 + kt * 32),
        (__attribute__((address_space(3))) unsigned int*)&d[wbase * 8], 16, 0, 0);
    __builtin_amdgcn_global_load_lds(
        (const __attribute__((address_space(1))) unsigned int*)(gA1 + kt * 32),
        (__attribute__((address_space(3))) unsigned int*)&d[(256 + wbase) * 8], 16, 0, 0);
  };
  auto stageB = [&](int slot, int kt) {
    unsigned short* d = sh + 8192 + slot * 4096;
    __builtin_amdgcn_global_load_lds(
        (const __attribute__((address_space(1))) unsigned int*)(gB0 + kt * 32),
        (__attribute__((address_space(3))) unsigned int*)&d[wbase * 8], 16, 0, 0);
    __builtin_amdgcn_global_load_lds(
        (const __attribute__((address_space(1))) unsigned int*)(gB1 + kt * 32),
        (__attribute__((address_space(3))) unsigned int*)&d[(256 + wbase) * 8], 16, 0, 0);
  };

  constexpr int nkt = K >> 5;  // 32
  stageA(0, 0); stageB(0, 0); stageB(1, 1);
  asm volatile("s_waitcnt vmcnt(2)" ::: "memory");   // A0,B0 landed; B1 in flight
  __builtin_amdgcn_s_barrier();
  __builtin_amdgcn_sched_barrier(0);

  int aR = 0, bR = 0;
  for (int kt = 0; kt < nkt; ++kt) {
    if (kt + 1 < nkt) stageA(aR ^ 1, kt + 1);
    if (kt + 2 < nkt) { int bW = bR + 2; if (bW >= 3) bW -= 3; stageB(bW, kt + 2); }
    const unsigned short* AsC = sh + aR * 4096;
    const unsigned short* BsC = sh + 8192 + bR * 4096;
    bf16x8 af[4], bfr[4];
#pragma unroll
    for (int m = 0; m < 4; ++m)
      af[m] = *(const bf16x8*)&AsC[(wr + m * 16 + l15) * 32 + rchk];
#pragma unroll
    for (int n = 0; n < 4; ++n)
      bfr[n] = *(const bf16x8*)&BsC[(wc + n * 16 + l15) * 32 + rchk];
#pragma unroll
    for (int m = 0; m < 4; ++m)
#pragma unroll
      for (int n = 0; n < 4; ++n)
        acc[m][n] = __builtin_amdgcn_mfma_f32_16x16x32_bf16(af[m], bfr[n], acc[m][n], 0, 0, 0);
    if (kt + 1 < nkt) {
      if (kt + 2 < nkt) asm volatile("s_waitcnt vmcnt(2)" ::: "memory");
      else              asm volatile("s_waitcnt vmcnt(0)" ::: "memory");
      __builtin_amdgcn_s_barrier();
      __builtin_amdgcn_sched_barrier(0);
    }
    aR ^= 1;
    bR = (bR + 1 == 3) ? 0 : bR + 1;
  }

  __builtin_amdgcn_s_barrier();   // ring reads done before C-restage overwrite
  __builtin_amdgcn_sched_barrier(0);

  // LDS-staged head-major epilogue (coalesced stores; cvt_pk for bf16).
#pragma unroll
  for (int n = 0; n < 4; ++n) {
    int col = wc + n * 16 + l15;                 // tile-local col (< 128)
    float bvv = bp[ccol + col];
    int hh = col >> 6, c64 = col & 63;
#pragma unroll
    for (int m = 0; m < 4; ++m) {
      int sl0 = (wr >> 2) + m * 4 + l4;          // s_local (j-independent)
      unsigned p01 = cvtpk((acc[m][n][0] + bvv) * scale, (acc[m][n][1] + bvv) * scale);
      unsigned p23 = cvtpk((acc[m][n][2] + bvv) * scale, (acc[m][n][3] + bvv) * scale);
      unsigned short ev[4] = {(unsigned short)p01, (unsigned short)(p01 >> 16),
                              (unsigned short)p23, (unsigned short)(p23 >> 16)};
#pragma unroll
      for (int j = 0; j < 4; ++j) {
        int or_ = (j * 2 + hh) * 32 + sl0;
        int bo = or_ * 128 + c64 * 2;
        *(unsigned short*)((char*)sh + (bo ^ ((or_ & 7) << 4))) = ev[j];
      }
    }
  }
  __syncthreads();
  {
    int s_local = tid & 31, grp = tid >> 5;      // grp = b2*2 + hh
    int b2 = grp >> 1, hh = grp & 1;
    int h = (ccol >> 6) + hh;
    unsigned short* po =
        out + ((size_t)(b2 * kNh + h) * kSeq + (rb >> 2) + s_local) * kDk;
    const int or_ = tid;
#pragma unroll
    for (int i = 0; i < 8; ++i) {
      int bo = or_ * 128 + i * 16;
      u16x8 vv = *(const u16x8*)((const char*)sh + (bo ^ ((or_ & 7) << 4)));
      *(u16x8*)(po + i * 8) = vv;
    }
  }
}

// Output projection: C[M,N] fp32 = A(head-major bf16) @ Wo^T + bo.
// Same A2/B3 ring + chunk swizzle; direct fp32 epilogue.
__global__ __launch_bounds__(256) void gemm_o(const unsigned short* __restrict__ Aw,
                                              const unsigned short* __restrict__ Bw,
                                              const float* __restrict__ bias,
                                              float* __restrict__ Cp) {
  constexpr int K = kDm, N = kDm;
  __shared__ unsigned short sh[20480];
  const int tid = (int)threadIdx.x;
  const int l = tid & 63;
  const int wbase = tid & ~63;
  const int bid = (int)blockIdx.x;
  const int lin = (bid & 7) * 128 + (bid >> 3);   // cb-fastest; Wo L2-fits
  const int rb = (lin >> 3) * 128, cb = (lin & 7) * 128;
  const int wr = ((tid >> 7) & 1) * 64;
  const int wc = ((tid >> 6) & 1) * 64;
  const int l15 = l & 15, l4 = l >> 4;

  const int rr0 = tid >> 2;
  const int c4p = (tid & 3) ^ (rr0 & 3);
  const int t0 = rb + rr0, t1 = t0 + 64;
  const unsigned short* gA0 =
      Aw + ((size_t)((t0 & 3) * kNh) * kSeq + (t0 >> 2)) * kDk + c4p * 8;
  const unsigned short* gA1 =
      Aw + ((size_t)((t1 & 3) * kNh) * kSeq + (t1 >> 2)) * kDk + c4p * 8;
  const unsigned short* gB0 = Bw + (size_t)(cb + rr0) * K + c4p * 8;
  const unsigned short* gB1 = gB0 + (size_t)64 * K;
  const int rchk = (l4 ^ (l15 & 3)) * 8;

  f32x4 acc[4][4] = {};

  auto stageA = [&](int slot, int kt) {
    unsigned short* d = sh + slot * 4096;
    size_t ko = (size_t)(kt >> 1) * ((size_t)kSeq * kDk) + (kt & 1) * 32;
    __builtin_amdgcn_global_load_lds(
        (const __attribute__((address_space(1))) unsigned int*)(gA0 + ko),
        (__attribute__((address_space(3))) unsigned int*)&d[wbase * 8], 16, 0, 0);
    __builtin_amdgcn_global_load_lds(
        (const __attribute__((address_space(1))) unsigned int*)(gA1 + ko),
        (__attribute__((address_space(3))) unsigned int*)&d[(256 + wbase) * 8], 16, 0, 0);
  };
  auto stageB = [&](int slot, int kt) {
    unsigned short* d = sh + 8192 + slot * 4096;
    __builtin_amdgcn_global_load_lds(
        (const __attribute__((address_space(1))) unsigned int*)(gB0 + kt * 32),
        (__attribute__((address_space(3))) unsigned int*)&d[wbase * 8], 16, 0, 0);
    __builtin_amdgcn_global_load_lds(
        (const __attribute__((address_space(1))) unsigned int*)(gB1 + kt * 32),
        (__attribute__((address_space(3))) unsigned int*)&d[(256 + wbase) * 8], 16, 0, 0);
  };

  constexpr int nkt = K >> 5;
  stageA(0, 0); stageB(0, 0); stageB(1, 1);
  asm volatile("s_waitcnt vmcnt(2)" ::: "memory");
  __builtin_amdgcn_s_barrier();
  __builtin_amdgcn_sched_barrier(0);

  int aR = 0, bR = 0;
  for (int kt = 0; kt < nkt; ++kt) {
    if (kt + 1 < nkt) stageA(aR ^ 1, kt + 1);
    if (kt + 2 < nkt) { int bW = bR + 2; if (bW >= 3) bW -= 3; stageB(bW, kt + 2); }
    const unsigned short* AsC = sh + aR * 4096;
    const unsigned short* BsC = sh + 8192 + bR * 4096;
    bf16x8 af[4], bfr[4];
#pragma unroll
    for (int m = 0; m < 4; ++m)
      af[m] = *(const bf16x8*)&AsC[(wr + m * 16 + l15) * 32 + rchk];
#pragma unroll
    for (int n = 0; n < 4; ++n)
      bfr[n] = *(const bf16x8*)&BsC[(wc + n * 16 + l15) * 32 + rchk];
#pragma unroll
    for (int m = 0; m < 4; ++m)
#pragma unroll
      for (int n = 0; n < 4; ++n)
        acc[m][n] = __builtin_amdgcn_mfma_f32_16x16x32_bf16(af[m], bfr[n], acc[m][n], 0, 0, 0);
    if (kt + 1 < nkt) {
      if (kt + 2 < nkt) asm volatile("s_waitcnt vmcnt(2)" ::: "memory");
      else              asm volatile("s_waitcnt vmcnt(0)" ::: "memory");
      __builtin_amdgcn_s_barrier();
      __builtin_amdgcn_sched_barrier(0);
    }
    aR ^= 1;
    bR = (bR + 1 == 3) ? 0 : bR + 1;
  }

#pragma unroll
  for (int n = 0; n < 4; ++n) {
    int col = cb + wc + n * 16 + l15;
    float bvv = bias[col];
#pragma unroll
    for (int m = 0; m < 4; ++m) {
      int row0 = rb + wr + m * 16 + l4 * 4;
#pragma unroll
      for (int j = 0; j < 4; ++j)
        Cp[(size_t)(row0 + j) * N + col] = acc[m][n][j] + bvv;
    }
  }
}

// C = A @ Bw^T + bias (fallback path only, small-ws).
template <int ALAY, int OHM>
__global__ __launch_bounds__(256) void gemm_bt(const void* __restrict__ Ap,
                                               const unsigned short* __restrict__ Bw,
                                               const float* __restrict__ bias,
                                               void* __restrict__ Cp, float scale) {
  constexpr int K = kDm, N = kDm;
  __shared__ unsigned short As[2][128 * 32];
  __shared__ unsigned short Bs[2][128 * 32];
  const int tid = (int)threadIdx.x;
  const int l = tid & 63;
  const int wbase = tid & ~63;
  const int bid = (int)blockIdx.x;
  const int lin = (bid & 7) * 128 + (bid >> 3);
  const int rb = (lin >> 3) * 128, cb = (lin & 7) * 128;
  const int wr = ((tid >> 7) & 1) * 64;
  const int wc = ((tid >> 6) & 1) * 64;
  const int l15 = l & 15, l4 = l >> 4;

  f32x4 acc[4][4] = {};

  auto stage = [&](int buf, int k0) {
    if constexpr (ALAY == 1) {
      const float* A = (const float*)Ap;
#pragma unroll
      for (int i = 0; i < 4; ++i) {
        int ci = tid + 256 * i;
        int rr = ci >> 3, c4 = ci & 7;
        f32x4 v = *(const f32x4*)(A + (size_t)(rb + rr) * K + (k0 + c4 * 4));
        u16x4 o;
        o[0] = f2bf(v[0]); o[1] = f2bf(v[1]); o[2] = f2bf(v[2]); o[3] = f2bf(v[3]);
        *(u16x4*)&As[buf][rr * 32 + c4 * 4] = o;
      }
    } else {
      const unsigned short* A = (const unsigned short*)Ap;
      int h = k0 >> 6, d0 = k0 & 63;
#pragma unroll
      for (int i = 0; i < 2; ++i) {
        int ch = i * 256 + tid;
        int rr = ch >> 2, cc = ch & 3;
        int t = rb + rr; int s = t >> 2, b2 = t & 3;
        const unsigned short* g =
            A + ((size_t)(b2 * kNh + h) * kSeq + s) * kDk + d0 + cc * 8;
        __builtin_amdgcn_global_load_lds(
            (const __attribute__((address_space(1))) unsigned int*)g,
            (__attribute__((address_space(3))) unsigned int*)&As[buf][(i * 256 + wbase) * 8],
            16, 0, 0);
      }
    }
#pragma unroll
    for (int i = 0; i < 2; ++i) {
      int ch = i * 256 + tid;
      int rr = ch >> 2, cc = ch & 3;
      const unsigned short* g = Bw + (size_t)(cb + rr) * K + (k0 + cc * 8);
      __builtin_amdgcn_global_load_lds(
          (const __attribute__((address_space(1))) unsigned int*)g,
          (__attribute__((address_space(3))) unsigned int*)&Bs[buf][(i * 256 + wbase) * 8],
          16, 0, 0);
    }
  };

  stage(0, 0);
  __syncthreads();
  int cur = 0;
  constexpr int nkt = K >> 5;
  for (int kt = 0; kt < nkt; ++kt) {
    if (kt + 1 < nkt) stage(cur ^ 1, (kt + 1) << 5);
    bf16x8 af[4], bfr[4];
#pragma unroll
    for (int m = 0; m < 4; ++m)
      af[m] = *(const bf16x8*)&As[cur][(wr + m * 16 + l15) * 32 + l4 * 8];
#pragma unroll
    for (int n = 0; n < 4; ++n)
      bfr[n] = *(const bf16x8*)&Bs[cur][(wc + n * 16 + l15) * 32 + l4 * 8];
#pragma unroll
    for (int m = 0; m < 4; ++m)
#pragma unroll
      for (int n = 0; n < 4; ++n)
        acc[m][n] = __builtin_amdgcn_mfma_f32_16x16x32_bf16(af[m], bfr[n], acc[m][n], 0, 0, 0);
    __syncthreads();
    cur ^= 1;
  }

#pragma unroll
  for (int n = 0; n < 4; ++n) {
    int col = cb + wc + n * 16 + l15;
    float bvv = bias[col];
    int h = col >> 6, dd = col & 63;
#pragma unroll
    for (int m = 0; m < 4; ++m) {
      int row0 = rb + wr + m * 16 + l4 * 4;
#pragma unroll
      for (int j = 0; j < 4; ++j) {
        float v = acc[m][n][j] + bvv;
        int t = row0 + j;
        if constexpr (OHM) {
          int s = t >> 2, b2 = t & 3;
          ((unsigned short*)Cp)[((size_t)(b2 * kNh + h) * kSeq + s) * kDk + dd] =
              f2bf(v * scale);
        } else {
          ((float*)Cp)[(size_t)t * N + col] = v;
        }
      }
    }
  }
}

// Block-diagonal flash attention, head-major (B*H, S, dk) in/out.
__global__ __launch_bounds__(256) void attn_blkdiag(const unsigned short* __restrict__ qw,
                                                    const unsigned short* __restrict__ kw,
                                                    const unsigned short* __restrict__ vw,
                                                    unsigned short* __restrict__ ow) {
  __shared__ unsigned short Kl[64 * 64];       // [kv_row][d]   (swizzled)
  __shared__ unsigned short Vt[64 * 64];       // [d][kv_row]   (transposed, swizzled)
  const int tid = (int)threadIdx.x;
  const int w = tid >> 6, l = tid & 63;
  const int l15 = l & 15, l4 = l >> 4;
  const int bid0 = (int)blockIdx.x;
  const int bid = (bid0 & 7) * 256 + (bid0 >> 3);   // XCD swizzle, 2048 % 8 == 0
  const int hf = bid & 1, c = (bid >> 1) & 15, bh = bid >> 5;
  const size_t base = ((size_t)bh * kSeq + c * kChk) * kDk;
  const unsigned short* qp = qw + base + (size_t)hf * 128 * kDk;
  const unsigned short* kp = kw + base;
  const unsigned short* vp = vw + base;

  bf16x8 q[2][2];
#pragma unroll
  for (int m = 0; m < 2; ++m)
#pragma unroll
    for (int kk = 0; kk < 2; ++kk)
      q[m][kk] = *(const bf16x8*)(qp + (w * 32 + m * 16 + l15) * 64 + kk * 32 + l4 * 8);

  float mst[2] = {-1e30f, -1e30f}, lst[2] = {0.f, 0.f};
  f32x4 oacc[2][4] = {};

  const int r = tid >> 2, c0 = (tid & 3) * 16;
  u16x8 kr0, kr1, vr0, vr1;
  {
    const unsigned short* kt = kp + tid * 16;
    kr0 = *(const u16x8*)kt; kr1 = *(const u16x8*)(kt + 8);
    const unsigned short* vt = vp + tid * 16;
    vr0 = *(const u16x8*)vt; vr1 = *(const u16x8*)(vt + 8);
  }

  for (int kb = 0; kb < 4; ++kb) {
    __syncthreads();
    {
      int bo = r * 128 + c0 * 2;
      *(u16x8*)((char*)Kl + swz(bo)) = kr0;
      *(u16x8*)((char*)Kl + swz(bo + 16)) = kr1;
#pragma unroll
      for (int j = 0; j < 8; ++j) {
        *(unsigned short*)((char*)Vt + swz((c0 + j) * 128 + r * 2)) = vr0[j];
        *(unsigned short*)((char*)Vt + swz((c0 + 8 + j) * 128 + r * 2)) = vr1[j];
      }
    }
    __syncthreads();
    if (kb < 3) {
      const unsigned short* kt = kp + (kb + 1) * (64 * kDk) + tid * 16;
      kr0 = *(const u16x8*)kt; kr1 = *(const u16x8*)(kt + 8);
      const unsigned short* vt = vp + (kb + 1) * (64 * kDk) + tid * 16;
      vr0 = *(const u16x8*)vt; vr1 = *(const u16x8*)(vt + 8);
    }

    f32x4 sacc[4][2] = {};
    __builtin_amdgcn_s_setprio(1);
#pragma unroll
    for (int kk = 0; kk < 2; ++kk) {
      bf16x8 kf[4];
#pragma unroll
      for (int kn = 0; kn < 4; ++kn) {
        int bo = (kn * 16 + l15) * 128 + (kk * 32 + l4 * 8) * 2;
        kf[kn] = *(const bf16x8*)((const char*)Kl + swz(bo));
      }
#pragma unroll
      for (int kn = 0; kn < 4; ++kn)
#pragma unroll
        for (int m = 0; m < 2; ++m)
          sacc[kn][m] = __builtin_amdgcn_mfma_f32_16x16x32_bf16(kf[kn], q[m][kk], sacc[kn][m], 0, 0, 0);
    }
    __builtin_amdgcn_s_setprio(0);

    unsigned pw[2][4][2];
    float cbq[2][4];
#pragma unroll
    for (int m = 0; m < 2; ++m) {
      float rm = -1e30f;
#pragma unroll
      for (int kn = 0; kn < 4; ++kn)
#pragma unroll
        for (int j = 0; j < 4; ++j) rm = fmaxf(rm, sacc[kn][m][j]);
      rm = fmaxf(rm, __shfl_xor(rm, 16, 64));
      rm = fmaxf(rm, __shfl_xor(rm, 32, 64));
      float mn = fmaxf(mst[m], rm);
      float corr = exp2f(mst[m] - mn);
      mst[m] = mn;
      float rs = 0.f;
#pragma unroll
      for (int kn = 0; kn < 4; ++kn) {
#pragma unroll
        for (int j = 0; j < 4; ++j) {
          float p = exp2f(sacc[kn][m][j] - mn);
          sacc[kn][m][j] = p;
          rs += p;
        }
        pw[m][kn][0] = cvtpk(sacc[kn][m][0], sacc[kn][m][1]);
        pw[m][kn][1] = cvtpk(sacc[kn][m][2], sacc[kn][m][3]);
      }
      rs += __shfl_xor(rs, 16, 64);
      rs += __shfl_xor(rs, 32, 64);
      lst[m] = lst[m] * corr + rs;
#pragma unroll
      for (int j = 0; j < 4; ++j) cbq[m][j] = __shfl(corr, l4 * 4 + j, 64);
#pragma unroll
      for (int n = 0; n < 4; ++n)
#pragma unroll
        for (int j = 0; j < 4; ++j) oacc[m][n][j] *= cbq[m][j];
    }

    __builtin_amdgcn_s_setprio(1);
#pragma unroll
    for (int kn = 0; kn < 4; ++kn) {
      bf16x4 vf[4];
#pragma unroll
      for (int n = 0; n < 4; ++n) {
        int bo = (n * 16 + l15) * 128 + (kn * 16 + l4 * 4) * 2;
        vf[n] = *(const bf16x4*)((const char*)Vt + swz(bo));
      }
#pragma unroll
      for (int m = 0; m < 2; ++m) {
        union { unsigned u[2]; bf16x4 h; } pk;
        pk.u[0] = pw[m][kn][0]; pk.u[1] = pw[m][kn][1];
#pragma unroll
        for (int n = 0; n < 4; ++n)
          oacc[m][n] = mfma16x16(pk.h, vf[n], oacc[m][n]);
      }
    }
    __builtin_amdgcn_s_setprio(0);
  }

  unsigned short* op = ow + base + (size_t)hf * 128 * kDk;
#pragma unroll
  for (int m = 0; m < 2; ++m) {
    float inv = 1.f / lst[m];
#pragma unroll
    for (int j = 0; j < 4; ++j) {
      float ib = __shfl(inv, l4 * 4 + j, 64);
      int srow = w * 32 + m * 16 + l4 * 4 + j;
#pragma unroll
      for (int n = 0; n < 4; ++n)
        op[(size_t)srow * 64 + n * 16 + l15] = f2bf(oacc[m][n][j] * ib);
    }
  }
}

}  // namespace

extern "C" void kernel_launch(void* const* d_in, const int* in_sizes, int n_in,
                              void* d_out, int out_size, void* d_ws, size_t ws_size,
                              hipStream_t stream) {
  const float* query = (const float*)d_in[0];
  const float* key   = (const float*)d_in[1];
  const float* value = (const float*)d_in[2];
  const float* Wq = (const float*)d_in[3];
  const float* bq = (const float*)d_in[4];
  const float* Wk = (const float*)d_in[5];
  const float* bk = (const float*)d_in[6];
  const float* Wv = (const float*)d_in[7];
  const float* bv = (const float*)d_in[8];
  const float* Wo = (const float*)d_in[9];
  const float* bo = (const float*)d_in[10];

  const float sQ = 0.125f * kLog2e;   // 1/sqrt(dk) * log2(e), folded into Q proj

  const size_t wsz = (size_t)kDm * kDm;          // 1M elems
  const size_t tsz = (size_t)kMr * kDm;          // 16M elems
  unsigned short* wsp = (unsigned short*)d_ws;
  unsigned short* wqb = wsp;                     // Wq|Wk|Wv|Wo contiguous
  unsigned short* wob = wqb + 3 * wsz;
  unsigned short* qws = wqb + 4 * wsz;
  unsigned short* kws = qws + tsz;
  unsigned short* vws = kws + tsz;
  unsigned short* x0  = vws + tsz;               // path A: qbf|kbf|vbf; path B: aws

  const size_t needA = (4 * wsz + 6 * tsz) * 2;  // 200 MB
  const size_t needB = (4 * wsz + 4 * tsz) * 2;  // 136 MB
  if (ws_size < needB) return;

  cvt4<<<dim3(4096), dim3(256), 0, stream>>>(Wq, Wk, Wv, Wo, wqb);

  if (ws_size >= needA) {
    unsigned short* qbf = x0;
    unsigned short* kbf = qbf + tsz;
    unsigned short* vbf = kbf + tsz;
    unsigned short* aws = qbf;                   // reuse after QKV GEMM consumes qbf
    cvt3<<<dim3(49152), dim3(256), 0, stream>>>(query, key, value, qbf);
    gemm_qkv<<<dim3(3072), 256, 0, stream>>>(qbf, kbf, vbf, wqb, bq, bk, bv, qws, sQ);
    attn_blkdiag<<<dim3(2048), 256, 0, stream>>>(qws, kws, vws, aws);
    gemm_o<<<dim3(1024), 256, 0, stream>>>(aws, wob, bo, (float*)d_out);
  } else {
    unsigned short* aws = x0;
    gemm_bt<1, 1><<<dim3(1024), 256, 0, stream>>>(query, wqb, bq, qws, sQ);
    gemm_bt<1, 1><<<dim3(1024), 256, 0, stream>>>(key,   wqb + wsz, bk, kws, 1.0f);
    gemm_bt<1, 1><<<dim3(1024), 256, 0, stream>>>(value, wqb + 2 * wsz, bv, vws, 1.0f);
    attn_blkdiag<<<dim3(2048), 256, 0, stream>>>(qws, kws, vws, aws);
    gemm_bt<2, 0><<<dim3(1024), 256, 0, stream>>>(aws, wob, bo, d_out, 1.0f);
  }
}

// Round 8
// 271.798 us; speedup vs baseline: 1.1562x; 1.1562x over previous
//
#include <hip/hip_runtime.h>
#include <hip/hip_bf16.h>

// MemoryEfficientMultiheadAttention: chunked (block-diagonal) MHA.
// S=4096, B=4, D=1024, H=16, dk=64, CHUNK=256.
// cvt(weights, qkv->bf16) -> fused QKV GEMM (8-phase 256x256 schedule, counted
// vmcnt, chunk-swizzled LDS, LDS-restaged head-major epilogue) -> flash attn
// (swapped QK^T, P-in-reg PV) -> out proj (A2/B3 ring).

namespace {

constexpr int kSeq = 4096, kB = 4, kDm = 1024, kNh = 16, kDk = 64, kChk = 256;
constexpr int kMr = kSeq * kB;       // 16384 GEMM rows
constexpr float kLog2e = 1.44269504088896340736f;

typedef __attribute__((ext_vector_type(8))) short bf16x8;
typedef __attribute__((ext_vector_type(4))) short bf16x4;
typedef __attribute__((ext_vector_type(4))) float f32x4;
typedef __attribute__((ext_vector_type(8))) unsigned short u16x8;
typedef __attribute__((ext_vector_type(4))) unsigned short u16x4;

#define AS1 __attribute__((address_space(1)))
#define AS3 __attribute__((address_space(3)))

__device__ __forceinline__ unsigned short f2bf(float x) {
  union { float f; unsigned u; } v; v.f = x;
  unsigned r = v.u + 0x7fffu + ((v.u >> 16) & 1u);   // RNE
  return (unsigned short)(r >> 16);
}
// HW packed f32->bf16 (RNE), 1 VALU op for 2 elements.
__device__ __forceinline__ unsigned cvtpk(float lo, float hi) {
  unsigned r;
  asm("v_cvt_pk_bf16_f32 %0, %1, %2" : "=v"(r) : "v"(lo), "v"(hi));
  return r;
}
// XOR swizzle for 128B-row-stride LDS tiles: xor byte bits 4-6 with row&7.
__device__ __forceinline__ int swz(int bo) { return bo ^ ((bo >> 3) & 0x70); }

__device__ __forceinline__ f32x4 mfma16x16(bf16x4 a, bf16x4 b, f32x4 c) {
#if __has_builtin(__builtin_amdgcn_mfma_f32_16x16x16bf16_1k)
  return __builtin_amdgcn_mfma_f32_16x16x16bf16_1k(a, b, c, 0, 0, 0);
#else
  asm volatile("v_mfma_f32_16x16x16_bf16 %0, %1, %2, %0\n\ts_nop 4"
               : "+v"(c) : "v"(a), "v"(b));
  return c;
#endif
}

// All four 1024x1024 weights -> bf16, dst contiguous (Wq|Wk|Wv|Wo).
__global__ __launch_bounds__(256) void cvt4(const float* __restrict__ s0,
                                            const float* __restrict__ s1,
                                            const float* __restrict__ s2,
                                            const float* __restrict__ s3,
                                            unsigned short* __restrict__ dst) {
  int i = blockIdx.x * 256 + threadIdx.x;          // 0 .. 4*2^18-1
  int t = i >> 18;
  int j = i & 0x3ffff;
  const float* s = (t == 0) ? s0 : (t == 1) ? s1 : (t == 2) ? s2 : s3;
  f32x4 v = *(const f32x4*)(s + (size_t)j * 4);
  u16x4 o;
  o[0] = f2bf(v[0]); o[1] = f2bf(v[1]); o[2] = f2bf(v[2]); o[3] = f2bf(v[3]);
  *(u16x4*)(dst + (size_t)i * 4) = o;
}

// query|key|value fp32 -> bf16, three contiguous 16M-elem tensors.
__global__ __launch_bounds__(256) void cvt3(const float* __restrict__ s0,
                                            const float* __restrict__ s1,
                                            const float* __restrict__ s2,
                                            unsigned short* __restrict__ dst) {
  size_t i = (size_t)blockIdx.x * 256 + threadIdx.x;   // 3 * 2^22 chunks
  int t = (int)(i >> 22);
  size_t j = i & 0x3fffff;
  const float* s = (t == 0) ? s0 : (t == 1) ? s1 : s2;
  f32x4 v = *(const f32x4*)(s + j * 4);
  u16x4 o;
  o[0] = f2bf(v[0]); o[1] = f2bf(v[1]); o[2] = f2bf(v[2]); o[3] = f2bf(v[3]);
  *(u16x4*)(dst + i * 4) = o;
}

// ---- Fused QKV projection, 8-phase 256x256 template (T3+T4+T2) ----
// Wcat rows 0..3071 = Wq|Wk|Wv. 768 blocks x 512 threads (8 waves, 2Mx4N).
// K=1024 -> 16 K-tiles of BK=64, 8 iterations x 8 phases (2 K-tiles/iter).
// LDS 128KB: 4 A-half-slots + 4 B-half-slots (128x64 bf16 each); slot(T,h) =
// (T&1)*2+h. Stage cadence: phase p0/p1 of tile T stage A(T+1,0/1); phase p3
// stages B(T+2,both). Gate vmcnt(4) once per K-tile (counted, no drain).
// 16B-chunk XOR swizzle: source g = c ^ (row&7), same XOR on ds_read.
__global__ __launch_bounds__(512, 2) void gemm_qkv8(
    const unsigned short* __restrict__ qbf, const unsigned short* __restrict__ kbf,
    const unsigned short* __restrict__ vbf, const unsigned short* __restrict__ Wcat,
    const float* __restrict__ bq, const float* __restrict__ bk,
    const float* __restrict__ bv, unsigned short* __restrict__ dst, float sQ) {
  constexpr int K = kDm, nkt = K / 64;   // 16
  __shared__ unsigned short sh[65536];   // 128 KB: A slots [0,32768), B [32768,65536)
  const int tid = (int)threadIdx.x;      // 0..511
  const int l = tid & 63;
  const int l15 = l & 15, l4 = l >> 4, l7 = l15 & 7;
  const int wid = tid >> 6, wm = wid >> 2, wn = wid & 3, wn1 = wn & 1;
  const int bid = (int)blockIdx.x;
  // XCD map (768 % 8 == 0): each XCD owns a fixed 8-rbi stripe (4MB A, L2-held)
  const int xcd = bid & 7, idx = bid >> 3;          // idx 0..95
  const int rbi = xcd * 8 + (idx & 7);              // 0..63
  const int cbi = idx >> 3;                         // 0..11
  const int mat = cbi >> 2, ccol = (cbi & 3) * 256;
  const float* bp = (mat == 0) ? bq : (mat == 1) ? bk : bv;
  const float scale = (mat == 0) ? sQ : 1.0f;
  const unsigned short* Ain = (mat == 0) ? qbf : (mat == 1) ? kbf : vbf;
  unsigned short* out = dst + (size_t)mat * kMr * kDm;

  // Per-thread staging bases. Thread stages chunks c=tid and c=tid+512 of each
  // 128x64 half (1024 16B-chunks): row = c>>3 (+64 for c2), col16 = c&7.
  // Source pre-swizzle: global chunk g = (c&7) ^ ((c>>3)&7) (same for both c).
  const int srow = tid >> 3;
  const int g16 = (tid & 7) ^ (srow & 7);
  const unsigned short* gA = Ain + (size_t)(rbi * 256 + srow) * K + g16 * 8;
  const unsigned short* gB = Wcat + (size_t)(cbi * 256 + srow) * K + g16 * 8;
  const int ldsbase = (tid & ~63) * 8;   // wave-uniform dest (+4096 for chunk 2)

  auto stageA = [&](int T, int h) {
    const unsigned short* s = gA + (size_t)h * (128 * K) + T * 64;
    unsigned short* d = sh + ((T & 1) * 2 + h) * 8192 + ldsbase;
    __builtin_amdgcn_global_load_lds((const AS1 unsigned int*)s, (AS3 unsigned int*)d, 16, 0, 0);
    __builtin_amdgcn_global_load_lds((const AS1 unsigned int*)(s + 64 * K),
                                     (AS3 unsigned int*)(d + 4096), 16, 0, 0);
  };
  auto stageB = [&](int T, int h) {
    const unsigned short* s = gB + (size_t)h * (128 * K) + T * 64;
    unsigned short* d = sh + 32768 + ((T & 1) * 2 + h) * 8192 + ldsbase;
    __builtin_amdgcn_global_load_lds((const AS1 unsigned int*)s, (AS3 unsigned int*)d, 16, 0, 0);
    __builtin_amdgcn_global_load_lds((const AS1 unsigned int*)(s + 64 * K),
                                     (AS3 unsigned int*)(d + 4096), 16, 0, 0);
  };

  f32x4 acc[8][4] = {};
  bf16x8 bfr[4];

  // Prologue: B(0) both halves, A(0) both, B(1) both -> gate vmcnt(4): tile 0
  // landed (B(1)'s 4 loads stay in flight). Matches steady-state FIFO shape.
  stageB(0, 0); stageB(0, 1);
  stageA(0, 0); stageA(0, 1);
  stageB(1, 0); stageB(1, 1);
  asm volatile("s_waitcnt vmcnt(4)" ::: "memory");
  __builtin_amdgcn_s_barrier();

  for (int it = 0; it < nkt / 2; ++it) {
#pragma unroll
    for (int tt = 0; tt < 2; ++tt) {
      const int T = 2 * it + tt;
      const unsigned short* Asl = sh + ((T & 1) * 2 + wm) * 8192;
      const unsigned short* Bsl = sh + 32768 + ((T & 1) * 2 + (wn >> 1)) * 8192;
#pragma unroll
      for (int p = 0; p < 4; ++p) {
        const int kk = p >> 1, mfh = p & 1;
        // ds-reads for this phase's fragments (swizzled chunk)
        bf16x8 af[4];
        const int sc = ((kk * 4 + l4) ^ l7) * 8;
        if (mfh == 0) {
#pragma unroll
          for (int nf = 0; nf < 4; ++nf)
            bfr[nf] = *(const bf16x8*)&Bsl[(wn1 * 64 + nf * 16 + l15) * 64 + sc];
        }
#pragma unroll
        for (int i = 0; i < 4; ++i)
          af[i] = *(const bf16x8*)&Asl[(mfh * 64 + i * 16 + l15) * 64 + sc];
        // stage prefetch per schedule (slots freed >=1 barrier ago)
        if (p == 0 && T + 1 < nkt) stageA(T + 1, 0);
        if (p == 1 && T + 1 < nkt) stageA(T + 1, 1);
        if (p == 3 && T + 2 < nkt) { stageB(T + 2, 0); stageB(T + 2, 1); }
        __builtin_amdgcn_s_barrier();
        __builtin_amdgcn_s_setprio(1);
#pragma unroll
        for (int i = 0; i < 4; ++i)
#pragma unroll
          for (int nf = 0; nf < 4; ++nf)
            acc[mfh * 4 + i][nf] =
                __builtin_amdgcn_mfma_f32_16x16x32_bf16(af[i], bfr[nf], acc[mfh * 4 + i][nf], 0, 0, 0);
        __builtin_amdgcn_s_setprio(0);
        if (p == 3 && T + 1 < nkt) {   // counted gate for next K-tile
          if (T + 2 < nkt) asm volatile("s_waitcnt vmcnt(4)" ::: "memory");
          else             asm volatile("s_waitcnt vmcnt(0)" ::: "memory");
        }
        __builtin_amdgcn_s_barrier();
      }
    }
  }

  // ---- Epilogue: restage 256x256 C into LDS (store-order + XOR swz), then
  // coalesced head-major stores. All prior loads drained by the final gates.
#pragma unroll
  for (int mf = 0; mf < 8; ++mf)
#pragma unroll
    for (int nf = 0; nf < 4; ++nf) {
      int col = wn * 64 + nf * 16 + l15;            // tile-local col 0..255
      float bvv = bp[ccol + col];
      int grpc = col >> 6;                          // head-local within tile
      int c16 = (col & 63) >> 3, pos = col & 7;
#pragma unroll
      for (int j = 0; j < 4; ++j) {
        int tl = wm * 128 + mf * 16 + l4 * 4 + j;   // tile-local row 0..255
        int grp = (tl & 3) * 4 + grpc;
        int u = (tl >> 2) * 8 + c16;
        int byte = (grp * 8192 + u * 16 + pos * 2) ^ (((u >> 3) & 7) << 4);
        *(unsigned short*)((char*)sh + byte) = f2bf((acc[mf][nf][j] + bvv) * scale);
      }
    }
  __syncthreads();
  {
    int inner = tid & 31, grp = tid >> 5;           // grp = b2*4 + hl
    int b2 = grp >> 2, hl = grp & 3;
    int h = (cbi & 3) * 4 + hl;
    unsigned short* po = out + ((size_t)(b2 * kNh + h) * kSeq + rbi * 64) * kDk;
#pragma unroll
    for (int i = 0; i < 16; ++i) {
      int u = i * 32 + inner;
      int byte = (grp * 8192 + u * 16) ^ (((u >> 3) & 7) << 4);
      u16x8 v = *(const u16x8*)((const char*)sh + byte);
      *(u16x8*)(po + u * 8) = v;
    }
  }
}

// Output projection: C[M,N] fp32 = A(head-major bf16) @ Wo^T + bo.
// A2/B3 ring + chunk swizzle; direct fp32 epilogue.
__global__ __launch_bounds__(256) void gemm_o(const unsigned short* __restrict__ Aw,
                                              const unsigned short* __restrict__ Bw,
                                              const float* __restrict__ bias,
                                              float* __restrict__ Cp) {
  constexpr int K = kDm, N = kDm;
  __shared__ unsigned short sh[20480];
  const int tid = (int)threadIdx.x;
  const int l = tid & 63;
  const int wbase = tid & ~63;
  const int bid = (int)blockIdx.x;
  const int lin = (bid & 7) * 128 + (bid >> 3);   // cb-fastest; Wo L2-fits
  const int rb = (lin >> 3) * 128, cb = (lin & 7) * 128;
  const int wr = ((tid >> 7) & 1) * 64;
  const int wc = ((tid >> 6) & 1) * 64;
  const int l15 = l & 15, l4 = l >> 4;

  const int rr0 = tid >> 2;
  const int c4p = (tid & 3) ^ (rr0 & 3);
  const int t0 = rb + rr0, t1 = t0 + 64;
  const unsigned short* gA0 =
      Aw + ((size_t)((t0 & 3) * kNh) * kSeq + (t0 >> 2)) * kDk + c4p * 8;
  const unsigned short* gA1 =
      Aw + ((size_t)((t1 & 3) * kNh) * kSeq + (t1 >> 2)) * kDk + c4p * 8;
  const unsigned short* gB0 = Bw + (size_t)(cb + rr0) * K + c4p * 8;
  const unsigned short* gB1 = gB0 + (size_t)64 * K;
  const int rchk = (l4 ^ (l15 & 3)) * 8;

  f32x4 acc[4][4] = {};

  auto stageA = [&](int slot, int kt) {
    unsigned short* d = sh + slot * 4096;
    size_t ko = (size_t)(kt >> 1) * ((size_t)kSeq * kDk) + (kt & 1) * 32;
    __builtin_amdgcn_global_load_lds((const AS1 unsigned int*)(gA0 + ko),
                                     (AS3 unsigned int*)&d[wbase * 8], 16, 0, 0);
    __builtin_amdgcn_global_load_lds((const AS1 unsigned int*)(gA1 + ko),
                                     (AS3 unsigned int*)&d[(256 + wbase) * 8], 16, 0, 0);
  };
  auto stageB = [&](int slot, int kt) {
    unsigned short* d = sh + 8192 + slot * 4096;
    __builtin_amdgcn_global_load_lds((const AS1 unsigned int*)(gB0 + kt * 32),
                                     (AS3 unsigned int*)&d[wbase * 8], 16, 0, 0);
    __builtin_amdgcn_global_load_lds((const AS1 unsigned int*)(gB1 + kt * 32),
                                     (AS3 unsigned int*)&d[(256 + wbase) * 8], 16, 0, 0);
  };

  constexpr int nkt = K >> 5;
  stageA(0, 0); stageB(0, 0); stageB(1, 1);
  asm volatile("s_waitcnt vmcnt(2)" ::: "memory");
  __builtin_amdgcn_s_barrier();
  __builtin_amdgcn_sched_barrier(0);

  int aR = 0, bR = 0;
  for (int kt = 0; kt < nkt; ++kt) {
    if (kt + 1 < nkt) stageA(aR ^ 1, kt + 1);
    if (kt + 2 < nkt) { int bW = bR + 2; if (bW >= 3) bW -= 3; stageB(bW, kt + 2); }
    const unsigned short* AsC = sh + aR * 4096;
    const unsigned short* BsC = sh + 8192 + bR * 4096;
    bf16x8 af[4], bfr[4];
#pragma unroll
    for (int m = 0; m < 4; ++m)
      af[m] = *(const bf16x8*)&AsC[(wr + m * 16 + l15) * 32 + rchk];
#pragma unroll
    for (int n = 0; n < 4; ++n)
      bfr[n] = *(const bf16x8*)&BsC[(wc + n * 16 + l15) * 32 + rchk];
#pragma unroll
    for (int m = 0; m < 4; ++m)
#pragma unroll
      for (int n = 0; n < 4; ++n)
        acc[m][n] = __builtin_amdgcn_mfma_f32_16x16x32_bf16(af[m], bfr[n], acc[m][n], 0, 0, 0);
    if (kt + 1 < nkt) {
      if (kt + 2 < nkt) asm volatile("s_waitcnt vmcnt(2)" ::: "memory");
      else              asm volatile("s_waitcnt vmcnt(0)" ::: "memory");
      __builtin_amdgcn_s_barrier();
      __builtin_amdgcn_sched_barrier(0);
    }
    aR ^= 1;
    bR = (bR + 1 == 3) ? 0 : bR + 1;
  }

#pragma unroll
  for (int n = 0; n < 4; ++n) {
    int col = cb + wc + n * 16 + l15;
    float bvv = bias[col];
#pragma unroll
    for (int m = 0; m < 4; ++m) {
      int row0 = rb + wr + m * 16 + l4 * 4;
#pragma unroll
      for (int j = 0; j < 4; ++j)
        Cp[(size_t)(row0 + j) * N + col] = acc[m][n][j] + bvv;
    }
  }
}

// C = A @ Bw^T + bias (fallback path only, small-ws).
template <int ALAY, int OHM>
__global__ __launch_bounds__(256) void gemm_bt(const void* __restrict__ Ap,
                                               const unsigned short* __restrict__ Bw,
                                               const float* __restrict__ bias,
                                               void* __restrict__ Cp, float scale) {
  constexpr int K = kDm, N = kDm;
  __shared__ unsigned short As[2][128 * 32];
  __shared__ unsigned short Bs[2][128 * 32];
  const int tid = (int)threadIdx.x;
  const int l = tid & 63;
  const int wbase = tid & ~63;
  const int bid = (int)blockIdx.x;
  const int lin = (bid & 7) * 128 + (bid >> 3);
  const int rb = (lin >> 3) * 128, cb = (lin & 7) * 128;
  const int wr = ((tid >> 7) & 1) * 64;
  const int wc = ((tid >> 6) & 1) * 64;
  const int l15 = l & 15, l4 = l >> 4;

  f32x4 acc[4][4] = {};

  auto stage = [&](int buf, int k0) {
    if constexpr (ALAY == 1) {
      const float* A = (const float*)Ap;
#pragma unroll
      for (int i = 0; i < 4; ++i) {
        int ci = tid + 256 * i;
        int rr = ci >> 3, c4 = ci & 7;
        f32x4 v = *(const f32x4*)(A + (size_t)(rb + rr) * K + (k0 + c4 * 4));
        u16x4 o;
        o[0] = f2bf(v[0]); o[1] = f2bf(v[1]); o[2] = f2bf(v[2]); o[3] = f2bf(v[3]);
        *(u16x4*)&As[buf][rr * 32 + c4 * 4] = o;
      }
    } else {
      const unsigned short* A = (const unsigned short*)Ap;
      int h = k0 >> 6, d0 = k0 & 63;
#pragma unroll
      for (int i = 0; i < 2; ++i) {
        int ch = i * 256 + tid;
        int rr = ch >> 2, cc = ch & 3;
        int t = rb + rr; int s = t >> 2, b2 = t & 3;
        const unsigned short* g =
            A + ((size_t)(b2 * kNh + h) * kSeq + s) * kDk + d0 + cc * 8;
        __builtin_amdgcn_global_load_lds((const AS1 unsigned int*)g,
                                         (AS3 unsigned int*)&As[buf][(i * 256 + wbase) * 8],
                                         16, 0, 0);
      }
    }
#pragma unroll
    for (int i = 0; i < 2; ++i) {
      int ch = i * 256 + tid;
      int rr = ch >> 2, cc = ch & 3;
      const unsigned short* g = Bw + (size_t)(cb + rr) * K + (k0 + cc * 8);
      __builtin_amdgcn_global_load_lds((const AS1 unsigned int*)g,
                                       (AS3 unsigned int*)&Bs[buf][(i * 256 + wbase) * 8],
                                       16, 0, 0);
    }
  };

  stage(0, 0);
  __syncthreads();
  int cur = 0;
  constexpr int nkt = K >> 5;
  for (int kt = 0; kt < nkt; ++kt) {
    if (kt + 1 < nkt) stage(cur ^ 1, (kt + 1) << 5);
    bf16x8 af[4], bfr[4];
#pragma unroll
    for (int m = 0; m < 4; ++m)
      af[m] = *(const bf16x8*)&As[cur][(wr + m * 16 + l15) * 32 + l4 * 8];
#pragma unroll
    for (int n = 0; n < 4; ++n)
      bfr[n] = *(const bf16x8*)&Bs[cur][(wc + n * 16 + l15) * 32 + l4 * 8];
#pragma unroll
    for (int m = 0; m < 4; ++m)
#pragma unroll
      for (int n = 0; n < 4; ++n)
        acc[m][n] = __builtin_amdgcn_mfma_f32_16x16x32_bf16(af[m], bfr[n], acc[m][n], 0, 0, 0);
    __syncthreads();
    cur ^= 1;
  }

#pragma unroll
  for (int n = 0; n < 4; ++n) {
    int col = cb + wc + n * 16 + l15;
    float bvv = bias[col];
    int h = col >> 6, dd = col & 63;
#pragma unroll
    for (int m = 0; m < 4; ++m) {
      int row0 = rb + wr + m * 16 + l4 * 4;
#pragma unroll
      for (int j = 0; j < 4; ++j) {
        float v = acc[m][n][j] + bvv;
        int t = row0 + j;
        if constexpr (OHM) {
          int s = t >> 2, b2 = t & 3;
          ((unsigned short*)Cp)[((size_t)(b2 * kNh + h) * kSeq + s) * kDk + dd] =
              f2bf(v * scale);
        } else {
          ((float*)Cp)[(size_t)t * N + col] = v;
        }
      }
    }
  }
}

// Block-diagonal flash attention, head-major (B*H, S, dk) in/out.
__global__ __launch_bounds__(256) void attn_blkdiag(const unsigned short* __restrict__ qw,
                                                    const unsigned short* __restrict__ kw,
                                                    const unsigned short* __restrict__ vw,
                                                    unsigned short* __restrict__ ow) {
  __shared__ unsigned short Kl[64 * 64];       // [kv_row][d]   (swizzled)
  __shared__ unsigned short Vt[64 * 64];       // [d][kv_row]   (transposed, swizzled)
  const int tid = (int)threadIdx.x;
  const int w = tid >> 6, l = tid & 63;
  const int l15 = l & 15, l4 = l >> 4;
  const int bid0 = (int)blockIdx.x;
  const int bid = (bid0 & 7) * 256 + (bid0 >> 3);   // XCD swizzle, 2048 % 8 == 0
  const int hf = bid & 1, c = (bid >> 1) & 15, bh = bid >> 5;
  const size_t base = ((size_t)bh * kSeq + c * kChk) * kDk;
  const unsigned short* qp = qw + base + (size_t)hf * 128 * kDk;
  const unsigned short* kp = kw + base;
  const unsigned short* vp = vw + base;

  bf16x8 q[2][2];
#pragma unroll
  for (int m = 0; m < 2; ++m)
#pragma unroll
    for (int kk = 0; kk < 2; ++kk)
      q[m][kk] = *(const bf16x8*)(qp + (w * 32 + m * 16 + l15) * 64 + kk * 32 + l4 * 8);

  float mst[2] = {-1e30f, -1e30f}, lst[2] = {0.f, 0.f};
  f32x4 oacc[2][4] = {};

  const int r = tid >> 2, c0 = (tid & 3) * 16;
  u16x8 kr0, kr1, vr0, vr1;
  {
    const unsigned short* kt = kp + tid * 16;
    kr0 = *(const u16x8*)kt; kr1 = *(const u16x8*)(kt + 8);
    const unsigned short* vt = vp + tid * 16;
    vr0 = *(const u16x8*)vt; vr1 = *(const u16x8*)(vt + 8);
  }

  for (int kb = 0; kb < 4; ++kb) {
    __syncthreads();
    {
      int bo = r * 128 + c0 * 2;
      *(u16x8*)((char*)Kl + swz(bo)) = kr0;
      *(u16x8*)((char*)Kl + swz(bo + 16)) = kr1;
#pragma unroll
      for (int j = 0; j < 8; ++j) {
        *(unsigned short*)((char*)Vt + swz((c0 + j) * 128 + r * 2)) = vr0[j];
        *(unsigned short*)((char*)Vt + swz((c0 + 8 + j) * 128 + r * 2)) = vr1[j];
      }
    }
    __syncthreads();
    if (kb < 3) {
      const unsigned short* kt = kp + (kb + 1) * (64 * kDk) + tid * 16;
      kr0 = *(const u16x8*)kt; kr1 = *(const u16x8*)(kt + 8);
      const unsigned short* vt = vp + (kb + 1) * (64 * kDk) + tid * 16;
      vr0 = *(const u16x8*)vt; vr1 = *(const u16x8*)(vt + 8);
    }

    f32x4 sacc[4][2] = {};
    __builtin_amdgcn_s_setprio(1);
#pragma unroll
    for (int kk = 0; kk < 2; ++kk) {
      bf16x8 kf[4];
#pragma unroll
      for (int kn = 0; kn < 4; ++kn) {
        int bo = (kn * 16 + l15) * 128 + (kk * 32 + l4 * 8) * 2;
        kf[kn] = *(const bf16x8*)((const char*)Kl + swz(bo));
      }
#pragma unroll
      for (int kn = 0; kn < 4; ++kn)
#pragma unroll
        for (int m = 0; m < 2; ++m)
          sacc[kn][m] = __builtin_amdgcn_mfma_f32_16x16x32_bf16(kf[kn], q[m][kk], sacc[kn][m], 0, 0, 0);
    }
    __builtin_amdgcn_s_setprio(0);

    unsigned pw[2][4][2];
    float cbq[2][4];
#pragma unroll
    for (int m = 0; m < 2; ++m) {
      float rm = -1e30f;
#pragma unroll
      for (int kn = 0; kn < 4; ++kn)
#pragma unroll
        for (int j = 0; j < 4; ++j) rm = fmaxf(rm, sacc[kn][m][j]);
      rm = fmaxf(rm, __shfl_xor(rm, 16, 64));
      rm = fmaxf(rm, __shfl_xor(rm, 32, 64));
      float mn = fmaxf(mst[m], rm);
      float corr = exp2f(mst[m] - mn);
      mst[m] = mn;
      float rs = 0.f;
#pragma unroll
      for (int kn = 0; kn < 4; ++kn) {
#pragma unroll
        for (int j = 0; j < 4; ++j) {
          float p = exp2f(sacc[kn][m][j] - mn);
          sacc[kn][m][j] = p;
          rs += p;
        }
        pw[m][kn][0] = cvtpk(sacc[kn][m][0], sacc[kn][m][1]);
        pw[m][kn][1] = cvtpk(sacc[kn][m][2], sacc[kn][m][3]);
      }
      rs += __shfl_xor(rs, 16, 64);
      rs += __shfl_xor(rs, 32, 64);
      lst[m] = lst[m] * corr + rs;
#pragma unroll
      for (int j = 0; j < 4; ++j) cbq[m][j] = __shfl(corr, l4 * 4 + j, 64);
#pragma unroll
      for (int n = 0; n < 4; ++n)
#pragma unroll
        for (int j = 0; j < 4; ++j) oacc[m][n][j] *= cbq[m][j];
    }

    __builtin_amdgcn_s_setprio(1);
#pragma unroll
    for (int kn = 0; kn < 4; ++kn) {
      bf16x4 vf[4];
#pragma unroll
      for (int n = 0; n < 4; ++n) {
        int bo = (n * 16 + l15) * 128 + (kn * 16 + l4 * 4) * 2;
        vf[n] = *(const bf16x4*)((const char*)Vt + swz(bo));
      }
#pragma unroll
      for (int m = 0; m < 2; ++m) {
        union { unsigned u[2]; bf16x4 h; } pk;
        pk.u[0] = pw[m][kn][0]; pk.u[1] = pw[m][kn][1];
#pragma unroll
        for (int n = 0; n < 4; ++n)
          oacc[m][n] = mfma16x16(pk.h, vf[n], oacc[m][n]);
      }
    }
    __builtin_amdgcn_s_setprio(0);
  }

  unsigned short* op = ow + base + (size_t)hf * 128 * kDk;
#pragma unroll
  for (int m = 0; m < 2; ++m) {
    float inv = 1.f / lst[m];
#pragma unroll
    for (int j = 0; j < 4; ++j) {
      float ib = __shfl(inv, l4 * 4 + j, 64);
      int srow = w * 32 + m * 16 + l4 * 4 + j;
#pragma unroll
      for (int n = 0; n < 4; ++n)
        op[(size_t)srow * 64 + n * 16 + l15] = f2bf(oacc[m][n][j] * ib);
    }
  }
}

}  // namespace

extern "C" void kernel_launch(void* const* d_in, const int* in_sizes, int n_in,
                              void* d_out, int out_size, void* d_ws, size_t ws_size,
                              hipStream_t stream) {
  const float* query = (const float*)d_in[0];
  const float* key   = (const float*)d_in[1];
  const float* value = (const float*)d_in[2];
  const float* Wq = (const float*)d_in[3];
  const float* bq = (const float*)d_in[4];
  const float* Wk = (const float*)d_in[5];
  const float* bk = (const float*)d_in[6];
  const float* Wv = (const float*)d_in[7];
  const float* bv = (const float*)d_in[8];
  const float* Wo = (const float*)d_in[9];
  const float* bo = (const float*)d_in[10];

  const float sQ = 0.125f * kLog2e;   // 1/sqrt(dk) * log2(e), folded into Q proj

  const size_t wsz = (size_t)kDm * kDm;          // 1M elems
  const size_t tsz = (size_t)kMr * kDm;          // 16M elems
  unsigned short* wsp = (unsigned short*)d_ws;
  unsigned short* wqb = wsp;                     // Wq|Wk|Wv|Wo contiguous
  unsigned short* wob = wqb + 3 * wsz;
  unsigned short* qws = wqb + 4 * wsz;
  unsigned short* kws = qws + tsz;
  unsigned short* vws = kws + tsz;
  unsigned short* x0  = vws + tsz;               // path A: qbf|kbf|vbf; path B: aws

  const size_t needA = (4 * wsz + 6 * tsz) * 2;  // 200 MB
  const size_t needB = (4 * wsz + 4 * tsz) * 2;  // 136 MB
  if (ws_size < needB) return;

  cvt4<<<dim3(4096), dim3(256), 0, stream>>>(Wq, Wk, Wv, Wo, wqb);

  if (ws_size >= needA) {
    unsigned short* qbf = x0;
    unsigned short* kbf = qbf + tsz;
    unsigned short* vbf = kbf + tsz;
    unsigned short* aws = qbf;                   // reuse after QKV GEMM consumes qbf
    cvt3<<<dim3(49152), dim3(256), 0, stream>>>(query, key, value, qbf);
    gemm_qkv8<<<dim3(768), dim3(512), 0, stream>>>(qbf, kbf, vbf, wqb, bq, bk, bv, qws, sQ);
    attn_blkdiag<<<dim3(2048), 256, 0, stream>>>(qws, kws, vws, aws);
    gemm_o<<<dim3(1024), 256, 0, stream>>>(aws, wob, bo, (float*)d_out);
  } else {
    unsigned short* aws = x0;
    gemm_bt<1, 1><<<dim3(1024), 256, 0, stream>>>(query, wqb, bq, qws, sQ);
    gemm_bt<1, 1><<<dim3(1024), 256, 0, stream>>>(key,   wqb + wsz, bk, kws, 1.0f);
    gemm_bt<1, 1><<<dim3(1024), 256, 0, stream>>>(value, wqb + 2 * wsz, bv, vws, 1.0f);
    attn_blkdiag<<<dim3(2048), 256, 0, stream>>>(qws, kws, vws, aws);
    gemm_bt<2, 0><<<dim3(1024), 256, 0, stream>>>(aws, wob, bo, d_out, 1.0f);
  }
}

// Round 9
// 258.758 us; speedup vs baseline: 1.2144x; 1.0504x over previous
//
#include <hip/hip_runtime.h>
#include <hip/hip_bf16.h>

// MemoryEfficientMultiheadAttention: chunked (block-diagonal) MHA.
// S=4096, B=4, D=1024, H=16, dk=64, CHUNK=256.
// cvt_all -> fused QKV GEMM (8-phase 256x256) -> flash attn (swapped QK^T,
// P-in-reg PV) -> out proj (8-phase 256x256, fp32 epilogue).

namespace {

constexpr int kSeq = 4096, kB = 4, kDm = 1024, kNh = 16, kDk = 64, kChk = 256;
constexpr int kMr = kSeq * kB;       // 16384 GEMM rows
constexpr float kLog2e = 1.44269504088896340736f;

typedef __attribute__((ext_vector_type(8))) short bf16x8;
typedef __attribute__((ext_vector_type(4))) short bf16x4;
typedef __attribute__((ext_vector_type(4))) float f32x4;
typedef __attribute__((ext_vector_type(8))) unsigned short u16x8;
typedef __attribute__((ext_vector_type(4))) unsigned short u16x4;

#define AS1 __attribute__((address_space(1)))
#define AS3 __attribute__((address_space(3)))

__device__ __forceinline__ unsigned short f2bf(float x) {
  union { float f; unsigned u; } v; v.f = x;
  unsigned r = v.u + 0x7fffu + ((v.u >> 16) & 1u);   // RNE
  return (unsigned short)(r >> 16);
}
// HW packed f32->bf16 (RNE), 1 VALU op for 2 elements.
__device__ __forceinline__ unsigned cvtpk(float lo, float hi) {
  unsigned r;
  asm("v_cvt_pk_bf16_f32 %0, %1, %2" : "=v"(r) : "v"(lo), "v"(hi));
  return r;
}
// XOR swizzle for 128B-row-stride LDS tiles: xor byte bits 4-6 with row&7.
__device__ __forceinline__ int swz(int bo) { return bo ^ ((bo >> 3) & 0x70); }

__device__ __forceinline__ f32x4 mfma16x16(bf16x4 a, bf16x4 b, f32x4 c) {
#if __has_builtin(__builtin_amdgcn_mfma_f32_16x16x16bf16_1k)
  return __builtin_amdgcn_mfma_f32_16x16x16bf16_1k(a, b, c, 0, 0, 0);
#else
  asm volatile("v_mfma_f32_16x16x16_bf16 %0, %1, %2, %0\n\ts_nop 4"
               : "+v"(c) : "v"(a), "v"(b));
  return c;
#endif
}

// All four 1024x1024 weights -> bf16 (fallback path).
__global__ __launch_bounds__(256) void cvt4(const float* __restrict__ s0,
                                            const float* __restrict__ s1,
                                            const float* __restrict__ s2,
                                            const float* __restrict__ s3,
                                            unsigned short* __restrict__ dst) {
  int i = blockIdx.x * 256 + threadIdx.x;          // 0 .. 4*2^18-1
  int t = i >> 18;
  int j = i & 0x3ffff;
  const float* s = (t == 0) ? s0 : (t == 1) ? s1 : (t == 2) ? s2 : s3;
  f32x4 v = *(const f32x4*)(s + (size_t)j * 4);
  u16x4 o;
  o[0] = f2bf(v[0]); o[1] = f2bf(v[1]); o[2] = f2bf(v[2]); o[3] = f2bf(v[3]);
  *(u16x4*)(dst + (size_t)i * 4) = o;
}

// One launch: 4 weights (4x1M) + q|k|v (3x16M) fp32 -> bf16.
__global__ __launch_bounds__(256) void cvt_all(const float* __restrict__ q,
                                               const float* __restrict__ k,
                                               const float* __restrict__ v,
                                               const float* __restrict__ w0,
                                               const float* __restrict__ w1,
                                               const float* __restrict__ w2,
                                               const float* __restrict__ w3,
                                               unsigned short* __restrict__ wdst,
                                               unsigned short* __restrict__ qkvdst) {
  size_t i = (size_t)blockIdx.x * 256 + threadIdx.x;
  const float* s;
  unsigned short* d;
  size_t j;
  if (i < ((size_t)1 << 20)) {                     // weights: 4 x 2^18 chunks
    int t = (int)(i >> 18); j = i & 0x3ffff;
    s = (t == 0) ? w0 : (t == 1) ? w1 : (t == 2) ? w2 : w3;
    d = wdst + (i << 2);
  } else {                                         // qkv: 3 x 2^22 chunks
    size_t ii = i - ((size_t)1 << 20);
    int t = (int)(ii >> 22); j = ii & 0x3fffff;
    s = (t == 0) ? q : (t == 1) ? k : v;
    d = qkvdst + (ii << 2);
  }
  f32x4 vv = *(const f32x4*)(s + j * 4);
  u16x4 o;
  o[0] = f2bf(vv[0]); o[1] = f2bf(vv[1]); o[2] = f2bf(vv[2]); o[3] = f2bf(vv[3]);
  *(u16x4*)d = o;
}

// ---- Fused QKV projection, 8-phase 256x256 template (T3+T4+T2) ----
// Wcat rows 0..3071 = Wq|Wk|Wv. 768 blocks x 512 threads (8 waves, 2Mx4N).
// K=1024 -> 16 K-tiles of BK=64. LDS 128KB: 4 A-half-slots + 4 B-half-slots;
// slot(T,h) = (T&1)*2+h. Phase p0/p1 of tile T stage A(T+1,0/1); p3 stages
// B(T+2,both). Gate vmcnt(4) once per K-tile. 16B-chunk XOR swizzle.
__global__ __launch_bounds__(512, 2) void gemm_qkv8(
    const unsigned short* __restrict__ qbf, const unsigned short* __restrict__ kbf,
    const unsigned short* __restrict__ vbf, const unsigned short* __restrict__ Wcat,
    const float* __restrict__ bq, const float* __restrict__ bk,
    const float* __restrict__ bv, unsigned short* __restrict__ dst, float sQ) {
  constexpr int K = kDm, nkt = K / 64;   // 16
  __shared__ unsigned short sh[65536];   // 128 KB: A slots [0,32768), B [32768,65536)
  const int tid = (int)threadIdx.x;      // 0..511
  const int l = tid & 63;
  const int l15 = l & 15, l4 = l >> 4, l7 = l15 & 7;
  const int wid = tid >> 6, wm = wid >> 2, wn = wid & 3, wn1 = wn & 1;
  const int bid = (int)blockIdx.x;
  const int xcd = bid & 7, idx = bid >> 3;          // idx 0..95
  const int rbi = xcd * 8 + (idx & 7);              // 0..63
  const int cbi = idx >> 3;                         // 0..11
  const int mat = cbi >> 2, ccol = (cbi & 3) * 256;
  const float* bp = (mat == 0) ? bq : (mat == 1) ? bk : bv;
  const float scale = (mat == 0) ? sQ : 1.0f;
  const unsigned short* Ain = (mat == 0) ? qbf : (mat == 1) ? kbf : vbf;
  unsigned short* out = dst + (size_t)mat * kMr * kDm;

  const int srow = tid >> 3;
  const int g16 = (tid & 7) ^ (srow & 7);
  const unsigned short* gA = Ain + (size_t)(rbi * 256 + srow) * K + g16 * 8;
  const unsigned short* gB = Wcat + (size_t)(cbi * 256 + srow) * K + g16 * 8;
  const int ldsbase = (tid & ~63) * 8;   // wave-uniform dest (+4096 for chunk 2)

  auto stageA = [&](int T, int h) {
    const unsigned short* s = gA + (size_t)h * (128 * K) + T * 64;
    unsigned short* d = sh + ((T & 1) * 2 + h) * 8192 + ldsbase;
    __builtin_amdgcn_global_load_lds((const AS1 unsigned int*)s, (AS3 unsigned int*)d, 16, 0, 0);
    __builtin_amdgcn_global_load_lds((const AS1 unsigned int*)(s + 64 * K),
                                     (AS3 unsigned int*)(d + 4096), 16, 0, 0);
  };
  auto stageB = [&](int T, int h) {
    const unsigned short* s = gB + (size_t)h * (128 * K) + T * 64;
    unsigned short* d = sh + 32768 + ((T & 1) * 2 + h) * 8192 + ldsbase;
    __builtin_amdgcn_global_load_lds((const AS1 unsigned int*)s, (AS3 unsigned int*)d, 16, 0, 0);
    __builtin_amdgcn_global_load_lds((const AS1 unsigned int*)(s + 64 * K),
                                     (AS3 unsigned int*)(d + 4096), 16, 0, 0);
  };

  f32x4 acc[8][4] = {};
  bf16x8 bfr[4];

  stageB(0, 0); stageB(0, 1);
  stageA(0, 0); stageA(0, 1);
  stageB(1, 0); stageB(1, 1);
  asm volatile("s_waitcnt vmcnt(4)" ::: "memory");
  __builtin_amdgcn_s_barrier();

  for (int it = 0; it < nkt / 2; ++it) {
#pragma unroll
    for (int tt = 0; tt < 2; ++tt) {
      const int T = 2 * it + tt;
      const unsigned short* Asl = sh + ((T & 1) * 2 + wm) * 8192;
      const unsigned short* Bsl = sh + 32768 + ((T & 1) * 2 + (wn >> 1)) * 8192;
#pragma unroll
      for (int p = 0; p < 4; ++p) {
        const int kk = p >> 1, mfh = p & 1;
        bf16x8 af[4];
        const int sc = ((kk * 4 + l4) ^ l7) * 8;
        if (mfh == 0) {
#pragma unroll
          for (int nf = 0; nf < 4; ++nf)
            bfr[nf] = *(const bf16x8*)&Bsl[(wn1 * 64 + nf * 16 + l15) * 64 + sc];
        }
#pragma unroll
        for (int i = 0; i < 4; ++i)
          af[i] = *(const bf16x8*)&Asl[(mfh * 64 + i * 16 + l15) * 64 + sc];
        if (p == 0 && T + 1 < nkt) stageA(T + 1, 0);
        if (p == 1 && T + 1 < nkt) stageA(T + 1, 1);
        if (p == 3 && T + 2 < nkt) { stageB(T + 2, 0); stageB(T + 2, 1); }
        __builtin_amdgcn_s_barrier();
        __builtin_amdgcn_s_setprio(1);
#pragma unroll
        for (int i = 0; i < 4; ++i)
#pragma unroll
          for (int nf = 0; nf < 4; ++nf)
            acc[mfh * 4 + i][nf] =
                __builtin_amdgcn_mfma_f32_16x16x32_bf16(af[i], bfr[nf], acc[mfh * 4 + i][nf], 0, 0, 0);
        __builtin_amdgcn_s_setprio(0);
        if (p == 3 && T + 1 < nkt) {
          if (T + 2 < nkt) asm volatile("s_waitcnt vmcnt(4)" ::: "memory");
          else             asm volatile("s_waitcnt vmcnt(0)" ::: "memory");
        }
        __builtin_amdgcn_s_barrier();
      }
    }
  }

  // Epilogue: restage 256x256 C into LDS (store-order + XOR swz), then
  // coalesced head-major stores.
#pragma unroll
  for (int mf = 0; mf < 8; ++mf)
#pragma unroll
    for (int nf = 0; nf < 4; ++nf) {
      int col = wn * 64 + nf * 16 + l15;            // tile-local col 0..255
      float bvv = bp[ccol + col];
      int grpc = col >> 6;
      int c16 = (col & 63) >> 3, pos = col & 7;
#pragma unroll
      for (int j = 0; j < 4; ++j) {
        int tl = wm * 128 + mf * 16 + l4 * 4 + j;   // tile-local row 0..255
        int grp = (tl & 3) * 4 + grpc;
        int u = (tl >> 2) * 8 + c16;
        int byte = (grp * 8192 + u * 16 + pos * 2) ^ (((u >> 3) & 7) << 4);
        *(unsigned short*)((char*)sh + byte) = f2bf((acc[mf][nf][j] + bvv) * scale);
      }
    }
  __syncthreads();
  {
    int inner = tid & 31, grp = tid >> 5;           // grp = b2*4 + hl
    int b2 = grp >> 2, hl = grp & 3;
    int h = (cbi & 3) * 4 + hl;
    unsigned short* po = out + ((size_t)(b2 * kNh + h) * kSeq + rbi * 64) * kDk;
#pragma unroll
    for (int i = 0; i < 16; ++i) {
      int u = i * 32 + inner;
      int byte = (grp * 8192 + u * 16) ^ (((u >> 3) & 7) << 4);
      u16x8 v = *(const u16x8*)((const char*)sh + byte);
      *(u16x8*)(po + u * 8) = v;
    }
  }
}

// ---- Output projection, 8-phase 256x256 template ----
// C[M,N] fp32 = A(head-major bf16) @ Wo^T + bo. 256 blocks (64 rbi x 4 cbi)
// = exactly 1/CU. K-tile T == head T in the head-major A layout, so the
// per-T source offset is the uniform T*kSeq*kDk. Direct fp32 epilogue.
__global__ __launch_bounds__(512, 2) void gemm_o8(const unsigned short* __restrict__ Aw,
                                                  const unsigned short* __restrict__ Bw,
                                                  const float* __restrict__ bias,
                                                  float* __restrict__ Cp) {
  constexpr int K = kDm, nkt = K / 64;   // 16
  __shared__ unsigned short sh[65536];
  const int tid = (int)threadIdx.x;
  const int l = tid & 63;
  const int l15 = l & 15, l4 = l >> 4, l7 = l15 & 7;
  const int wid = tid >> 6, wm = wid >> 2, wn = wid & 3, wn1 = wn & 1;
  const int bid = (int)blockIdx.x;
  const int xcd = bid & 7, idx = bid >> 3;          // idx 0..31
  const int rbi = xcd * 8 + (idx & 7);              // 0..63
  const int cbi = idx >> 3;                         // 0..3
  const int rb = rbi * 256, cb = cbi * 256;

  const int srow = tid >> 3;
  const int g16 = (tid & 7) ^ (srow & 7);
  // A bases for (half h, sub i): row t = rb + h*128 + srow + 64*i.
  size_t abase[2][2];
#pragma unroll
  for (int h = 0; h < 2; ++h)
#pragma unroll
    for (int i = 0; i < 2; ++i) {
      int t = rb + h * 128 + srow + 64 * i;
      abase[h][i] = ((size_t)((t & 3) * kNh) * kSeq + (t >> 2)) * kDk + g16 * 8;
    }
  const unsigned short* gB = Bw + (size_t)(cb + srow) * K + g16 * 8;
  const int ldsbase = (tid & ~63) * 8;

  auto stageA = [&](int T, int h) {
    unsigned short* d = sh + ((T & 1) * 2 + h) * 8192 + ldsbase;
    size_t ko = (size_t)T * ((size_t)kSeq * kDk);   // head T
    __builtin_amdgcn_global_load_lds((const AS1 unsigned int*)(Aw + abase[h][0] + ko),
                                     (AS3 unsigned int*)d, 16, 0, 0);
    __builtin_amdgcn_global_load_lds((const AS1 unsigned int*)(Aw + abase[h][1] + ko),
                                     (AS3 unsigned int*)(d + 4096), 16, 0, 0);
  };
  auto stageB = [&](int T, int h) {
    const unsigned short* s = gB + (size_t)h * (128 * K) + T * 64;
    unsigned short* d = sh + 32768 + ((T & 1) * 2 + h) * 8192 + ldsbase;
    __builtin_amdgcn_global_load_lds((const AS1 unsigned int*)s, (AS3 unsigned int*)d, 16, 0, 0);
    __builtin_amdgcn_global_load_lds((const AS1 unsigned int*)(s + 64 * K),
                                     (AS3 unsigned int*)(d + 4096), 16, 0, 0);
  };

  f32x4 acc[8][4] = {};
  bf16x8 bfr[4];

  stageB(0, 0); stageB(0, 1);
  stageA(0, 0); stageA(0, 1);
  stageB(1, 0); stageB(1, 1);
  asm volatile("s_waitcnt vmcnt(4)" ::: "memory");
  __builtin_amdgcn_s_barrier();

  for (int it = 0; it < nkt / 2; ++it) {
#pragma unroll
    for (int tt = 0; tt < 2; ++tt) {
      const int T = 2 * it + tt;
      const unsigned short* Asl = sh + ((T & 1) * 2 + wm) * 8192;
      const unsigned short* Bsl = sh + 32768 + ((T & 1) * 2 + (wn >> 1)) * 8192;
#pragma unroll
      for (int p = 0; p < 4; ++p) {
        const int kk = p >> 1, mfh = p & 1;
        bf16x8 af[4];
        const int sc = ((kk * 4 + l4) ^ l7) * 8;
        if (mfh == 0) {
#pragma unroll
          for (int nf = 0; nf < 4; ++nf)
            bfr[nf] = *(const bf16x8*)&Bsl[(wn1 * 64 + nf * 16 + l15) * 64 + sc];
        }
#pragma unroll
        for (int i = 0; i < 4; ++i)
          af[i] = *(const bf16x8*)&Asl[(mfh * 64 + i * 16 + l15) * 64 + sc];
        if (p == 0 && T + 1 < nkt) stageA(T + 1, 0);
        if (p == 1 && T + 1 < nkt) stageA(T + 1, 1);
        if (p == 3 && T + 2 < nkt) { stageB(T + 2, 0); stageB(T + 2, 1); }
        __builtin_amdgcn_s_barrier();
        __builtin_amdgcn_s_setprio(1);
#pragma unroll
        for (int i = 0; i < 4; ++i)
#pragma unroll
          for (int nf = 0; nf < 4; ++nf)
            acc[mfh * 4 + i][nf] =
                __builtin_amdgcn_mfma_f32_16x16x32_bf16(af[i], bfr[nf], acc[mfh * 4 + i][nf], 0, 0, 0);
        __builtin_amdgcn_s_setprio(0);
        if (p == 3 && T + 1 < nkt) {
          if (T + 2 < nkt) asm volatile("s_waitcnt vmcnt(4)" ::: "memory");
          else             asm volatile("s_waitcnt vmcnt(0)" ::: "memory");
        }
        __builtin_amdgcn_s_barrier();
      }
    }
  }

  // Direct fp32 epilogue (row-major, 64B segments per 16-lane group).
#pragma unroll
  for (int nf = 0; nf < 4; ++nf) {
    int col = cb + wn * 64 + nf * 16 + l15;
    float bvv = bias[col];
#pragma unroll
    for (int mf = 0; mf < 8; ++mf) {
      int row0 = rb + wm * 128 + mf * 16 + l4 * 4;
#pragma unroll
      for (int j = 0; j < 4; ++j)
        Cp[(size_t)(row0 + j) * kDm + col] = acc[mf][nf][j] + bvv;
    }
  }
}

// C = A @ Bw^T + bias (fallback path only, small-ws).
template <int ALAY, int OHM>
__global__ __launch_bounds__(256) void gemm_bt(const void* __restrict__ Ap,
                                               const unsigned short* __restrict__ Bw,
                                               const float* __restrict__ bias,
                                               void* __restrict__ Cp, float scale) {
  constexpr int K = kDm, N = kDm;
  __shared__ unsigned short As[2][128 * 32];
  __shared__ unsigned short Bs[2][128 * 32];
  const int tid = (int)threadIdx.x;
  const int l = tid & 63;
  const int wbase = tid & ~63;
  const int bid = (int)blockIdx.x;
  const int lin = (bid & 7) * 128 + (bid >> 3);
  const int rb = (lin >> 3) * 128, cb = (lin & 7) * 128;
  const int wr = ((tid >> 7) & 1) * 64;
  const int wc = ((tid >> 6) & 1) * 64;
  const int l15 = l & 15, l4 = l >> 4;

  f32x4 acc[4][4] = {};

  auto stage = [&](int buf, int k0) {
    if constexpr (ALAY == 1) {
      const float* A = (const float*)Ap;
#pragma unroll
      for (int i = 0; i < 4; ++i) {
        int ci = tid + 256 * i;
        int rr = ci >> 3, c4 = ci & 7;
        f32x4 v = *(const f32x4*)(A + (size_t)(rb + rr) * K + (k0 + c4 * 4));
        u16x4 o;
        o[0] = f2bf(v[0]); o[1] = f2bf(v[1]); o[2] = f2bf(v[2]); o[3] = f2bf(v[3]);
        *(u16x4*)&As[buf][rr * 32 + c4 * 4] = o;
      }
    } else {
      const unsigned short* A = (const unsigned short*)Ap;
      int h = k0 >> 6, d0 = k0 & 63;
#pragma unroll
      for (int i = 0; i < 2; ++i) {
        int ch = i * 256 + tid;
        int rr = ch >> 2, cc = ch & 3;
        int t = rb + rr; int s = t >> 2, b2 = t & 3;
        const unsigned short* g =
            A + ((size_t)(b2 * kNh + h) * kSeq + s) * kDk + d0 + cc * 8;
        __builtin_amdgcn_global_load_lds((const AS1 unsigned int*)g,
                                         (AS3 unsigned int*)&As[buf][(i * 256 + wbase) * 8],
                                         16, 0, 0);
      }
    }
#pragma unroll
    for (int i = 0; i < 2; ++i) {
      int ch = i * 256 + tid;
      int rr = ch >> 2, cc = ch & 3;
      const unsigned short* g = Bw + (size_t)(cb + rr) * K + (k0 + cc * 8);
      __builtin_amdgcn_global_load_lds((const AS1 unsigned int*)g,
                                       (AS3 unsigned int*)&Bs[buf][(i * 256 + wbase) * 8],
                                       16, 0, 0);
    }
  };

  stage(0, 0);
  __syncthreads();
  int cur = 0;
  constexpr int nkt = K >> 5;
  for (int kt = 0; kt < nkt; ++kt) {
    if (kt + 1 < nkt) stage(cur ^ 1, (kt + 1) << 5);
    bf16x8 af[4], bfr[4];
#pragma unroll
    for (int m = 0; m < 4; ++m)
      af[m] = *(const bf16x8*)&As[cur][(wr + m * 16 + l15) * 32 + l4 * 8];
#pragma unroll
    for (int n = 0; n < 4; ++n)
      bfr[n] = *(const bf16x8*)&Bs[cur][(wc + n * 16 + l15) * 32 + l4 * 8];
#pragma unroll
    for (int m = 0; m < 4; ++m)
#pragma unroll
      for (int n = 0; n < 4; ++n)
        acc[m][n] = __builtin_amdgcn_mfma_f32_16x16x32_bf16(af[m], bfr[n], acc[m][n], 0, 0, 0);
    __syncthreads();
    cur ^= 1;
  }

#pragma unroll
  for (int n = 0; n < 4; ++n) {
    int col = cb + wc + n * 16 + l15;
    float bvv = bias[col];
    int h = col >> 6, dd = col & 63;
#pragma unroll
    for (int m = 0; m < 4; ++m) {
      int row0 = rb + wr + m * 16 + l4 * 4;
#pragma unroll
      for (int j = 0; j < 4; ++j) {
        float v = acc[m][n][j] + bvv;
        int t = row0 + j;
        if constexpr (OHM) {
          int s = t >> 2, b2 = t & 3;
          ((unsigned short*)Cp)[((size_t)(b2 * kNh + h) * kSeq + s) * kDk + dd] =
              f2bf(v * scale);
        } else {
          ((float*)Cp)[(size_t)t * N + col] = v;
        }
      }
    }
  }
}

// Block-diagonal flash attention, head-major (B*H, S, dk) in/out.
__global__ __launch_bounds__(256) void attn_blkdiag(const unsigned short* __restrict__ qw,
                                                    const unsigned short* __restrict__ kw,
                                                    const unsigned short* __restrict__ vw,
                                                    unsigned short* __restrict__ ow) {
  __shared__ unsigned short Kl[64 * 64];       // [kv_row][d]   (swizzled)
  __shared__ unsigned short Vt[64 * 64];       // [d][kv_row]   (transposed, swizzled)
  const int tid = (int)threadIdx.x;
  const int w = tid >> 6, l = tid & 63;
  const int l15 = l & 15, l4 = l >> 4;
  const int bid0 = (int)blockIdx.x;
  const int bid = (bid0 & 7) * 256 + (bid0 >> 3);   // XCD swizzle, 2048 % 8 == 0
  const int hf = bid & 1, c = (bid >> 1) & 15, bh = bid >> 5;
  const size_t base = ((size_t)bh * kSeq + c * kChk) * kDk;
  const unsigned short* qp = qw + base + (size_t)hf * 128 * kDk;
  const unsigned short* kp = kw + base;
  const unsigned short* vp = vw + base;

  bf16x8 q[2][2];
#pragma unroll
  for (int m = 0; m < 2; ++m)
#pragma unroll
    for (int kk = 0; kk < 2; ++kk)
      q[m][kk] = *(const bf16x8*)(qp + (w * 32 + m * 16 + l15) * 64 + kk * 32 + l4 * 8);

  float mst[2] = {-1e30f, -1e30f}, lst[2] = {0.f, 0.f};
  f32x4 oacc[2][4] = {};

  const int r = tid >> 2, c0 = (tid & 3) * 16;
  u16x8 kr0, kr1, vr0, vr1;
  {
    const unsigned short* kt = kp + tid * 16;
    kr0 = *(const u16x8*)kt; kr1 = *(const u16x8*)(kt + 8);
    const unsigned short* vt = vp + tid * 16;
    vr0 = *(const u16x8*)vt; vr1 = *(const u16x8*)(vt + 8);
  }

  for (int kb = 0; kb < 4; ++kb) {
    __syncthreads();
    {
      int bo = r * 128 + c0 * 2;
      *(u16x8*)((char*)Kl + swz(bo)) = kr0;
      *(u16x8*)((char*)Kl + swz(bo + 16)) = kr1;
#pragma unroll
      for (int j = 0; j < 8; ++j) {
        *(unsigned short*)((char*)Vt + swz((c0 + j) * 128 + r * 2)) = vr0[j];
        *(unsigned short*)((char*)Vt + swz((c0 + 8 + j) * 128 + r * 2)) = vr1[j];
      }
    }
    __syncthreads();
    if (kb < 3) {
      const unsigned short* kt = kp + (kb + 1) * (64 * kDk) + tid * 16;
      kr0 = *(const u16x8*)kt; kr1 = *(const u16x8*)(kt + 8);
      const unsigned short* vt = vp + (kb + 1) * (64 * kDk) + tid * 16;
      vr0 = *(const u16x8*)vt; vr1 = *(const u16x8*)(vt + 8);
    }

    f32x4 sacc[4][2] = {};
    __builtin_amdgcn_s_setprio(1);
#pragma unroll
    for (int kk = 0; kk < 2; ++kk) {
      bf16x8 kf[4];
#pragma unroll
      for (int kn = 0; kn < 4; ++kn) {
        int bo = (kn * 16 + l15) * 128 + (kk * 32 + l4 * 8) * 2;
        kf[kn] = *(const bf16x8*)((const char*)Kl + swz(bo));
      }
#pragma unroll
      for (int kn = 0; kn < 4; ++kn)
#pragma unroll
        for (int m = 0; m < 2; ++m)
          sacc[kn][m] = __builtin_amdgcn_mfma_f32_16x16x32_bf16(kf[kn], q[m][kk], sacc[kn][m], 0, 0, 0);
    }
    __builtin_amdgcn_s_setprio(0);

    unsigned pw[2][4][2];
    float cbq[2][4];
#pragma unroll
    for (int m = 0; m < 2; ++m) {
      float rm = -1e30f;
#pragma unroll
      for (int kn = 0; kn < 4; ++kn)
#pragma unroll
        for (int j = 0; j < 4; ++j) rm = fmaxf(rm, sacc[kn][m][j]);
      rm = fmaxf(rm, __shfl_xor(rm, 16, 64));
      rm = fmaxf(rm, __shfl_xor(rm, 32, 64));
      float mn = fmaxf(mst[m], rm);
      float corr = exp2f(mst[m] - mn);
      mst[m] = mn;
      float rs = 0.f;
#pragma unroll
      for (int kn = 0; kn < 4; ++kn) {
#pragma unroll
        for (int j = 0; j < 4; ++j) {
          float p = exp2f(sacc[kn][m][j] - mn);
          sacc[kn][m][j] = p;
          rs += p;
        }
        pw[m][kn][0] = cvtpk(sacc[kn][m][0], sacc[kn][m][1]);
        pw[m][kn][1] = cvtpk(sacc[kn][m][2], sacc[kn][m][3]);
      }
      rs += __shfl_xor(rs, 16, 64);
      rs += __shfl_xor(rs, 32, 64);
      lst[m] = lst[m] * corr + rs;
#pragma unroll
      for (int j = 0; j < 4; ++j) cbq[m][j] = __shfl(corr, l4 * 4 + j, 64);
#pragma unroll
      for (int n = 0; n < 4; ++n)
#pragma unroll
        for (int j = 0; j < 4; ++j) oacc[m][n][j] *= cbq[m][j];
    }

    __builtin_amdgcn_s_setprio(1);
#pragma unroll
    for (int kn = 0; kn < 4; ++kn) {
      bf16x4 vf[4];
#pragma unroll
      for (int n = 0; n < 4; ++n) {
        int bo = (n * 16 + l15) * 128 + (kn * 16 + l4 * 4) * 2;
        vf[n] = *(const bf16x4*)((const char*)Vt + swz(bo));
      }
#pragma unroll
      for (int m = 0; m < 2; ++m) {
        union { unsigned u[2]; bf16x4 h; } pk;
        pk.u[0] = pw[m][kn][0]; pk.u[1] = pw[m][kn][1];
#pragma unroll
        for (int n = 0; n < 4; ++n)
          oacc[m][n] = mfma16x16(pk.h, vf[n], oacc[m][n]);
      }
    }
    __builtin_amdgcn_s_setprio(0);
  }

  unsigned short* op = ow + base + (size_t)hf * 128 * kDk;
#pragma unroll
  for (int m = 0; m < 2; ++m) {
    float inv = 1.f / lst[m];
#pragma unroll
    for (int j = 0; j < 4; ++j) {
      float ib = __shfl(inv, l4 * 4 + j, 64);
      int srow = w * 32 + m * 16 + l4 * 4 + j;
#pragma unroll
      for (int n = 0; n < 4; ++n)
        op[(size_t)srow * 64 + n * 16 + l15] = f2bf(oacc[m][n][j] * ib);
    }
  }
}

}  // namespace

extern "C" void kernel_launch(void* const* d_in, const int* in_sizes, int n_in,
                              void* d_out, int out_size, void* d_ws, size_t ws_size,
                              hipStream_t stream) {
  const float* query = (const float*)d_in[0];
  const float* key   = (const float*)d_in[1];
  const float* value = (const float*)d_in[2];
  const float* Wq = (const float*)d_in[3];
  const float* bq = (const float*)d_in[4];
  const float* Wk = (const float*)d_in[5];
  const float* bk = (const float*)d_in[6];
  const float* Wv = (const float*)d_in[7];
  const float* bv = (const float*)d_in[8];
  const float* Wo = (const float*)d_in[9];
  const float* bo = (const float*)d_in[10];

  const float sQ = 0.125f * kLog2e;   // 1/sqrt(dk) * log2(e), folded into Q proj

  const size_t wsz = (size_t)kDm * kDm;          // 1M elems
  const size_t tsz = (size_t)kMr * kDm;          // 16M elems
  unsigned short* wsp = (unsigned short*)d_ws;
  unsigned short* wqb = wsp;                     // Wq|Wk|Wv|Wo contiguous
  unsigned short* wob = wqb + 3 * wsz;
  unsigned short* qws = wqb + 4 * wsz;
  unsigned short* kws = qws + tsz;
  unsigned short* vws = kws + tsz;
  unsigned short* x0  = vws + tsz;               // path A: qbf|kbf|vbf; path B: aws

  const size_t needA = (4 * wsz + 6 * tsz) * 2;  // 200 MB
  const size_t needB = (4 * wsz + 4 * tsz) * 2;  // 136 MB
  if (ws_size < needB) return;

  if (ws_size >= needA) {
    unsigned short* qbf = x0;
    unsigned short* kbf = qbf + tsz;
    unsigned short* vbf = kbf + tsz;
    unsigned short* aws = qbf;                   // reuse after QKV GEMM consumes qbf
    cvt_all<<<dim3(53248), dim3(256), 0, stream>>>(query, key, value, Wq, Wk, Wv, Wo,
                                                   wqb, qbf);
    gemm_qkv8<<<dim3(768), dim3(512), 0, stream>>>(qbf, kbf, vbf, wqb, bq, bk, bv, qws, sQ);
    attn_blkdiag<<<dim3(2048), 256, 0, stream>>>(qws, kws, vws, aws);
    gemm_o8<<<dim3(256), dim3(512), 0, stream>>>(aws, wob, bo, (float*)d_out);
  } else {
    unsigned short* aws = x0;
    cvt4<<<dim3(4096), dim3(256), 0, stream>>>(Wq, Wk, Wv, Wo, wqb);
    gemm_bt<1, 1><<<dim3(1024), 256, 0, stream>>>(query, wqb, bq, qws, sQ);
    gemm_bt<1, 1><<<dim3(1024), 256, 0, stream>>>(key,   wqb + wsz, bk, kws, 1.0f);
    gemm_bt<1, 1><<<dim3(1024), 256, 0, stream>>>(value, wqb + 2 * wsz, bv, vws, 1.0f);
    attn_blkdiag<<<dim3(2048), 256, 0, stream>>>(qws, kws, vws, aws);
    gemm_bt<2, 0><<<dim3(1024), 256, 0, stream>>>(aws, wob, bo, d_out, 1.0f);
  }
}

// Round 10
// 245.554 us; speedup vs baseline: 1.2797x; 1.0538x over previous
//
#include <hip/hip_runtime.h>
#include <hip/hip_bf16.h>

// MemoryEfficientMultiheadAttention: chunked (block-diagonal) MHA.
// S=4096, B=4, D=1024, H=16, dk=64, CHUNK=256.
// cvt(weights only) -> fused QKV GEMM (8-phase 256x256, A = fp32 inputs with
// fused bf16 convert in staging) -> flash attn (swapped QK^T, P-in-reg PV)
// -> out proj (8-phase 256x256, fp32 epilogue).

namespace {

constexpr int kSeq = 4096, kB = 4, kDm = 1024, kNh = 16, kDk = 64, kChk = 256;
constexpr int kMr = kSeq * kB;       // 16384 GEMM rows
constexpr float kLog2e = 1.44269504088896340736f;

typedef __attribute__((ext_vector_type(8))) short bf16x8;
typedef __attribute__((ext_vector_type(4))) short bf16x4;
typedef __attribute__((ext_vector_type(4))) float f32x4;
typedef __attribute__((ext_vector_type(8))) unsigned short u16x8;
typedef __attribute__((ext_vector_type(4))) unsigned short u16x4;
typedef __attribute__((ext_vector_type(4))) unsigned u32x4;

#define AS1 __attribute__((address_space(1)))
#define AS3 __attribute__((address_space(3)))

__device__ __forceinline__ unsigned short f2bf(float x) {
  union { float f; unsigned u; } v; v.f = x;
  unsigned r = v.u + 0x7fffu + ((v.u >> 16) & 1u);   // RNE
  return (unsigned short)(r >> 16);
}
// HW packed f32->bf16 (RNE): D[15:0]=bf16(lo), D[31:16]=bf16(hi).
__device__ __forceinline__ unsigned cvtpk(float lo, float hi) {
  unsigned r;
  asm("v_cvt_pk_bf16_f32 %0, %1, %2" : "=v"(r) : "v"(lo), "v"(hi));
  return r;
}
// XOR swizzle for 128B-row-stride LDS tiles: xor byte bits 4-6 with row&7.
__device__ __forceinline__ int swz(int bo) { return bo ^ ((bo >> 3) & 0x70); }

__device__ __forceinline__ f32x4 mfma16x16(bf16x4 a, bf16x4 b, f32x4 c) {
#if __has_builtin(__builtin_amdgcn_mfma_f32_16x16x16bf16_1k)
  return __builtin_amdgcn_mfma_f32_16x16x16bf16_1k(a, b, c, 0, 0, 0);
#else
  asm volatile("v_mfma_f32_16x16x16_bf16 %0, %1, %2, %0\n\ts_nop 4"
               : "+v"(c) : "v"(a), "v"(b));
  return c;
#endif
}

// All four 1024x1024 weights -> bf16, dst contiguous (Wq|Wk|Wv|Wo).
__global__ __launch_bounds__(256) void cvt4(const float* __restrict__ s0,
                                            const float* __restrict__ s1,
                                            const float* __restrict__ s2,
                                            const float* __restrict__ s3,
                                            unsigned short* __restrict__ dst) {
  int i = blockIdx.x * 256 + threadIdx.x;          // 0 .. 4*2^18-1
  int t = i >> 18;
  int j = i & 0x3ffff;
  const float* s = (t == 0) ? s0 : (t == 1) ? s1 : (t == 2) ? s2 : s3;
  f32x4 v = *(const f32x4*)(s + (size_t)j * 4);
  u16x4 o;
  o[0] = f2bf(v[0]); o[1] = f2bf(v[1]); o[2] = f2bf(v[2]); o[3] = f2bf(v[3]);
  *(u16x4*)(dst + (size_t)i * 4) = o;
}

// ---- Fused QKV projection, 8-phase 256x256 template (T3+T4+T2) ----
// A = ORIGINAL fp32 inputs (q/k/v): fused convert in staging. Per half-tile
// each thread loads 4 f32x4 at p0/p1 (issue-early), converts via cvt_pk and
// ds_write_b128 at p3 (write-late). LDS content invariant unchanged:
// chunk(row,c) = global chunk c^(row&7) -> existing swizzled reads work.
// B = bf16 Wcat via global_load_lds (source pre-swizzled). Counted gates:
// compiler's vmcnt wait for the A-regs (FIFO) subsumes B(T+1); explicit
// lgkmcnt(0) publishes ds_writes before the phase-closing barrier.
__global__ __launch_bounds__(512, 2) void gemm_qkv8(
    const float* __restrict__ qf, const float* __restrict__ kf,
    const float* __restrict__ vf, const unsigned short* __restrict__ Wcat,
    const float* __restrict__ bq, const float* __restrict__ bk,
    const float* __restrict__ bv, unsigned short* __restrict__ dst, float sQ) {
  constexpr int K = kDm, nkt = K / 64;   // 16
  __shared__ unsigned short sh[65536];   // 128 KB: A slots [0,32768), B [32768,65536)
  const int tid = (int)threadIdx.x;      // 0..511
  const int l = tid & 63;
  const int l15 = l & 15, l4 = l >> 4, l7 = l15 & 7;
  const int wid = tid >> 6, wm = wid >> 2, wn = wid & 3, wn1 = wn & 1;
  const int bid = (int)blockIdx.x;
  const int xcd = bid & 7, idx = bid >> 3;          // idx 0..95
  const int rbi = xcd * 8 + (idx & 7);              // 0..63
  const int cbi = idx >> 3;                         // 0..11
  const int mat = cbi >> 2, ccol = (cbi & 3) * 256;
  const float* bp = (mat == 0) ? bq : (mat == 1) ? bk : bv;
  const float scale = (mat == 0) ? sQ : 1.0f;
  const float* Ain = (mat == 0) ? qf : (mat == 1) ? kf : vf;
  unsigned short* out = dst + (size_t)mat * kMr * kDm;

  // A staging: thread owns row arow, bf16-chunks (ac2, ac2+1) of each half.
  const int arow = tid >> 2;                        // 0..127
  const int ac2 = (tid & 3) * 2;                    // 0,2,4,6
  const float* gA = Ain + (size_t)(rbi * 256 + arow) * K + ac2 * 8;
  const int awc0 = (ac2 ^ (arow & 7)) * 8;          // write chunk-XOR (shorts)
  const int awc1 = ((ac2 + 1) ^ (arow & 7)) * 8;
  // B staging: gload_lds, source pre-swizzled.
  const int srow = tid >> 3;
  const int g16 = (tid & 7) ^ (srow & 7);
  const unsigned short* gB = Wcat + (size_t)(cbi * 256 + srow) * K + g16 * 8;
  const int ldsbase = (tid & ~63) * 8;

  auto stageB = [&](int T, int h) {
    const unsigned short* s = gB + (size_t)h * (128 * K) + T * 64;
    unsigned short* d = sh + 32768 + ((T & 1) * 2 + h) * 8192 + ldsbase;
    __builtin_amdgcn_global_load_lds((const AS1 unsigned int*)s, (AS3 unsigned int*)d, 16, 0, 0);
    __builtin_amdgcn_global_load_lds((const AS1 unsigned int*)(s + 64 * K),
                                     (AS3 unsigned int*)(d + 4096), 16, 0, 0);
  };
  auto loadA = [&](f32x4* r, int T, int h) {
    const float* s = gA + (size_t)h * (128 * K) + T * 64;
    r[0] = *(const f32x4*)s;
    r[1] = *(const f32x4*)(s + 4);
    r[2] = *(const f32x4*)(s + 8);
    r[3] = *(const f32x4*)(s + 12);
  };
  auto writeA = [&](const f32x4* r, int T, int h) {
    unsigned short* d = sh + ((T & 1) * 2 + h) * 8192 + arow * 64;
    u32x4 w0 = {cvtpk(r[0][0], r[0][1]), cvtpk(r[0][2], r[0][3]),
                cvtpk(r[1][0], r[1][1]), cvtpk(r[1][2], r[1][3])};
    u32x4 w1 = {cvtpk(r[2][0], r[2][1]), cvtpk(r[2][2], r[2][3]),
                cvtpk(r[3][0], r[3][1]), cvtpk(r[3][2], r[3][3])};
    *(u32x4*)(d + awc0) = w0;
    *(u32x4*)(d + awc1) = w1;
  };

  f32x4 acc[8][4] = {};
  f32x4 aA[4], aB[4];
  bf16x8 bfr[4];

  // Prologue: A(0) regs -> B(0),B(1) issued -> write A(0) (compiler waits the
  // A loads; FIFO leaves B in flight) -> lgkm -> vmcnt(4): B(0) landed.
  loadA(aA, 0, 0);
  loadA(aB, 0, 1);
  stageB(0, 0); stageB(0, 1);
  stageB(1, 0); stageB(1, 1);
  writeA(aA, 0, 0);
  writeA(aB, 0, 1);
  asm volatile("s_waitcnt lgkmcnt(0)" ::: "memory");
  asm volatile("s_waitcnt vmcnt(4)" ::: "memory");
  __builtin_amdgcn_s_barrier();

  for (int it = 0; it < nkt / 2; ++it) {
#pragma unroll
    for (int tt = 0; tt < 2; ++tt) {
      const int T = 2 * it + tt;
      const unsigned short* Asl = sh + ((T & 1) * 2 + wm) * 8192;
      const unsigned short* Bsl = sh + 32768 + ((T & 1) * 2 + (wn >> 1)) * 8192;
#pragma unroll
      for (int p = 0; p < 4; ++p) {
        const int kk = p >> 1, mfh = p & 1;
        bf16x8 af[4];
        const int sc = ((kk * 4 + l4) ^ l7) * 8;
        if (mfh == 0) {
#pragma unroll
          for (int nf = 0; nf < 4; ++nf)
            bfr[nf] = *(const bf16x8*)&Bsl[(wn1 * 64 + nf * 16 + l15) * 64 + sc];
        }
#pragma unroll
        for (int i = 0; i < 4; ++i)
          af[i] = *(const bf16x8*)&Asl[(mfh * 64 + i * 16 + l15) * 64 + sc];
        if (p == 0 && T + 1 < nkt) {
          loadA(aA, T + 1, 0);
          __builtin_amdgcn_sched_barrier(0);   // pin issue-early
        }
        if (p == 1 && T + 1 < nkt) {
          loadA(aB, T + 1, 1);
          __builtin_amdgcn_sched_barrier(0);
        }
        if (p == 3) {
          if (T + 2 < nkt) { stageB(T + 2, 0); stageB(T + 2, 1); }
          if (T + 1 < nkt) {            // compiler vmcnt-waits the A regs here
            writeA(aA, T + 1, 0);
            writeA(aB, T + 1, 1);
          }
        }
        __builtin_amdgcn_s_barrier();
        __builtin_amdgcn_s_setprio(1);
#pragma unroll
        for (int i = 0; i < 4; ++i)
#pragma unroll
          for (int nf = 0; nf < 4; ++nf)
            acc[mfh * 4 + i][nf] =
                __builtin_amdgcn_mfma_f32_16x16x32_bf16(af[i], bfr[nf], acc[mfh * 4 + i][nf], 0, 0, 0);
        __builtin_amdgcn_s_setprio(0);
        if (p == 3)
          asm volatile("s_waitcnt lgkmcnt(0)" ::: "memory");  // publish A writes
        __builtin_amdgcn_s_barrier();
      }
    }
  }

  // Epilogue: restage 256x256 C into LDS (store-order + XOR swz), then
  // coalesced head-major stores. All VMEM/LDS drained by the final gates.
#pragma unroll
  for (int mf = 0; mf < 8; ++mf)
#pragma unroll
    for (int nf = 0; nf < 4; ++nf) {
      int col = wn * 64 + nf * 16 + l15;            // tile-local col 0..255
      float bvv = bp[ccol + col];
      int grpc = col >> 6;
      int c16 = (col & 63) >> 3, pos = col & 7;
      unsigned p01 = cvtpk((acc[mf][nf][0] + bvv) * scale, (acc[mf][nf][1] + bvv) * scale);
      unsigned p23 = cvtpk((acc[mf][nf][2] + bvv) * scale, (acc[mf][nf][3] + bvv) * scale);
      unsigned short ev[4] = {(unsigned short)p01, (unsigned short)(p01 >> 16),
                              (unsigned short)p23, (unsigned short)(p23 >> 16)};
#pragma unroll
      for (int j = 0; j < 4; ++j) {
        int tl = wm * 128 + mf * 16 + l4 * 4 + j;   // tile-local row 0..255
        int grp = (tl & 3) * 4 + grpc;
        int u = (tl >> 2) * 8 + c16;
        int byte = (grp * 8192 + u * 16 + pos * 2) ^ (((u >> 3) & 7) << 4);
        *(unsigned short*)((char*)sh + byte) = ev[j];
      }
    }
  __syncthreads();
  {
    int inner = tid & 31, grp = tid >> 5;           // grp = b2*4 + hl
    int b2 = grp >> 2, hl = grp & 3;
    int h = (cbi & 3) * 4 + hl;
    unsigned short* po = out + ((size_t)(b2 * kNh + h) * kSeq + rbi * 64) * kDk;
#pragma unroll
    for (int i = 0; i < 16; ++i) {
      int u = i * 32 + inner;
      int byte = (grp * 8192 + u * 16) ^ (((u >> 3) & 7) << 4);
      u16x8 v = *(const u16x8*)((const char*)sh + byte);
      *(u16x8*)(po + u * 8) = v;
    }
  }
}

// ---- Output projection, 8-phase 256x256 template ----
// C[M,N] fp32 = A(head-major bf16) @ Wo^T + bo. 256 blocks = 1/CU.
__global__ __launch_bounds__(512, 2) void gemm_o8(const unsigned short* __restrict__ Aw,
                                                  const unsigned short* __restrict__ Bw,
                                                  const float* __restrict__ bias,
                                                  float* __restrict__ Cp) {
  constexpr int K = kDm, nkt = K / 64;   // 16
  __shared__ unsigned short sh[65536];
  const int tid = (int)threadIdx.x;
  const int l = tid & 63;
  const int l15 = l & 15, l4 = l >> 4, l7 = l15 & 7;
  const int wid = tid >> 6, wm = wid >> 2, wn = wid & 3, wn1 = wn & 1;
  const int bid = (int)blockIdx.x;
  const int xcd = bid & 7, idx = bid >> 3;          // idx 0..31
  const int rbi = xcd * 8 + (idx & 7);              // 0..63
  const int cbi = idx >> 3;                         // 0..3
  const int rb = rbi * 256, cb = cbi * 256;

  const int srow = tid >> 3;
  const int g16 = (tid & 7) ^ (srow & 7);
  size_t abase[2][2];
#pragma unroll
  for (int h = 0; h < 2; ++h)
#pragma unroll
    for (int i = 0; i < 2; ++i) {
      int t = rb + h * 128 + srow + 64 * i;
      abase[h][i] = ((size_t)((t & 3) * kNh) * kSeq + (t >> 2)) * kDk + g16 * 8;
    }
  const unsigned short* gB = Bw + (size_t)(cb + srow) * K + g16 * 8;
  const int ldsbase = (tid & ~63) * 8;

  auto stageA = [&](int T, int h) {
    unsigned short* d = sh + ((T & 1) * 2 + h) * 8192 + ldsbase;
    size_t ko = (size_t)T * ((size_t)kSeq * kDk);   // head T
    __builtin_amdgcn_global_load_lds((const AS1 unsigned int*)(Aw + abase[h][0] + ko),
                                     (AS3 unsigned int*)d, 16, 0, 0);
    __builtin_amdgcn_global_load_lds((const AS1 unsigned int*)(Aw + abase[h][1] + ko),
                                     (AS3 unsigned int*)(d + 4096), 16, 0, 0);
  };
  auto stageB = [&](int T, int h) {
    const unsigned short* s = gB + (size_t)h * (128 * K) + T * 64;
    unsigned short* d = sh + 32768 + ((T & 1) * 2 + h) * 8192 + ldsbase;
    __builtin_amdgcn_global_load_lds((const AS1 unsigned int*)s, (AS3 unsigned int*)d, 16, 0, 0);
    __builtin_amdgcn_global_load_lds((const AS1 unsigned int*)(s + 64 * K),
                                     (AS3 unsigned int*)(d + 4096), 16, 0, 0);
  };

  f32x4 acc[8][4] = {};
  bf16x8 bfr[4];

  stageB(0, 0); stageB(0, 1);
  stageA(0, 0); stageA(0, 1);
  stageB(1, 0); stageB(1, 1);
  asm volatile("s_waitcnt vmcnt(4)" ::: "memory");
  __builtin_amdgcn_s_barrier();

  for (int it = 0; it < nkt / 2; ++it) {
#pragma unroll
    for (int tt = 0; tt < 2; ++tt) {
      const int T = 2 * it + tt;
      const unsigned short* Asl = sh + ((T & 1) * 2 + wm) * 8192;
      const unsigned short* Bsl = sh + 32768 + ((T & 1) * 2 + (wn >> 1)) * 8192;
#pragma unroll
      for (int p = 0; p < 4; ++p) {
        const int kk = p >> 1, mfh = p & 1;
        bf16x8 af[4];
        const int sc = ((kk * 4 + l4) ^ l7) * 8;
        if (mfh == 0) {
#pragma unroll
          for (int nf = 0; nf < 4; ++nf)
            bfr[nf] = *(const bf16x8*)&Bsl[(wn1 * 64 + nf * 16 + l15) * 64 + sc];
        }
#pragma unroll
        for (int i = 0; i < 4; ++i)
          af[i] = *(const bf16x8*)&Asl[(mfh * 64 + i * 16 + l15) * 64 + sc];
        if (p == 0 && T + 1 < nkt) stageA(T + 1, 0);
        if (p == 1 && T + 1 < nkt) stageA(T + 1, 1);
        if (p == 3 && T + 2 < nkt) { stageB(T + 2, 0); stageB(T + 2, 1); }
        __builtin_amdgcn_s_barrier();
        __builtin_amdgcn_s_setprio(1);
#pragma unroll
        for (int i = 0; i < 4; ++i)
#pragma unroll
          for (int nf = 0; nf < 4; ++nf)
            acc[mfh * 4 + i][nf] =
                __builtin_amdgcn_mfma_f32_16x16x32_bf16(af[i], bfr[nf], acc[mfh * 4 + i][nf], 0, 0, 0);
        __builtin_amdgcn_s_setprio(0);
        if (p == 3 && T + 1 < nkt) {
          if (T + 2 < nkt) asm volatile("s_waitcnt vmcnt(4)" ::: "memory");
          else             asm volatile("s_waitcnt vmcnt(0)" ::: "memory");
        }
        __builtin_amdgcn_s_barrier();
      }
    }
  }

#pragma unroll
  for (int nf = 0; nf < 4; ++nf) {
    int col = cb + wn * 64 + nf * 16 + l15;
    float bvv = bias[col];
#pragma unroll
    for (int mf = 0; mf < 8; ++mf) {
      int row0 = rb + wm * 128 + mf * 16 + l4 * 4;
#pragma unroll
      for (int j = 0; j < 4; ++j)
        Cp[(size_t)(row0 + j) * kDm + col] = acc[mf][nf][j] + bvv;
    }
  }
}

// Block-diagonal flash attention, head-major (B*H, S, dk) in/out.
__global__ __launch_bounds__(256) void attn_blkdiag(const unsigned short* __restrict__ qw,
                                                    const unsigned short* __restrict__ kw,
                                                    const unsigned short* __restrict__ vw,
                                                    unsigned short* __restrict__ ow) {
  __shared__ unsigned short Kl[64 * 64];       // [kv_row][d]   (swizzled)
  __shared__ unsigned short Vt[64 * 64];       // [d][kv_row]   (transposed, swizzled)
  const int tid = (int)threadIdx.x;
  const int w = tid >> 6, l = tid & 63;
  const int l15 = l & 15, l4 = l >> 4;
  const int bid0 = (int)blockIdx.x;
  const int bid = (bid0 & 7) * 256 + (bid0 >> 3);   // XCD swizzle, 2048 % 8 == 0
  const int hf = bid & 1, c = (bid >> 1) & 15, bh = bid >> 5;
  const size_t base = ((size_t)bh * kSeq + c * kChk) * kDk;
  const unsigned short* qp = qw + base + (size_t)hf * 128 * kDk;
  const unsigned short* kp = kw + base;
  const unsigned short* vp = vw + base;

  bf16x8 q[2][2];
#pragma unroll
  for (int m = 0; m < 2; ++m)
#pragma unroll
    for (int kk = 0; kk < 2; ++kk)
      q[m][kk] = *(const bf16x8*)(qp + (w * 32 + m * 16 + l15) * 64 + kk * 32 + l4 * 8);

  float mst[2] = {-1e30f, -1e30f}, lst[2] = {0.f, 0.f};
  f32x4 oacc[2][4] = {};

  const int r = tid >> 2, c0 = (tid & 3) * 16;
  u16x8 kr0, kr1, vr0, vr1;
  {
    const unsigned short* kt = kp + tid * 16;
    kr0 = *(const u16x8*)kt; kr1 = *(const u16x8*)(kt + 8);
    const unsigned short* vt = vp + tid * 16;
    vr0 = *(const u16x8*)vt; vr1 = *(const u16x8*)(vt + 8);
  }

  for (int kb = 0; kb < 4; ++kb) {
    __syncthreads();
    {
      int bo = r * 128 + c0 * 2;
      *(u16x8*)((char*)Kl + swz(bo)) = kr0;
      *(u16x8*)((char*)Kl + swz(bo + 16)) = kr1;
#pragma unroll
      for (int j = 0; j < 8; ++j) {
        *(unsigned short*)((char*)Vt + swz((c0 + j) * 128 + r * 2)) = vr0[j];
        *(unsigned short*)((char*)Vt + swz((c0 + 8 + j) * 128 + r * 2)) = vr1[j];
      }
    }
    __syncthreads();
    if (kb < 3) {
      const unsigned short* kt = kp + (kb + 1) * (64 * kDk) + tid * 16;
      kr0 = *(const u16x8*)kt; kr1 = *(const u16x8*)(kt + 8);
      const unsigned short* vt = vp + (kb + 1) * (64 * kDk) + tid * 16;
      vr0 = *(const u16x8*)vt; vr1 = *(const u16x8*)(vt + 8);
    }

    f32x4 sacc[4][2] = {};
    __builtin_amdgcn_s_setprio(1);
#pragma unroll
    for (int kk = 0; kk < 2; ++kk) {
      bf16x8 kf[4];
#pragma unroll
      for (int kn = 0; kn < 4; ++kn) {
        int bo = (kn * 16 + l15) * 128 + (kk * 32 + l4 * 8) * 2;
        kf[kn] = *(const bf16x8*)((const char*)Kl + swz(bo));
      }
#pragma unroll
      for (int kn = 0; kn < 4; ++kn)
#pragma unroll
        for (int m = 0; m < 2; ++m)
          sacc[kn][m] = __builtin_amdgcn_mfma_f32_16x16x32_bf16(kf[kn], q[m][kk], sacc[kn][m], 0, 0, 0);
    }
    __builtin_amdgcn_s_setprio(0);

    unsigned pw[2][4][2];
    float cbq[2][4];
#pragma unroll
    for (int m = 0; m < 2; ++m) {
      float rm = -1e30f;
#pragma unroll
      for (int kn = 0; kn < 4; ++kn)
#pragma unroll
        for (int j = 0; j < 4; ++j) rm = fmaxf(rm, sacc[kn][m][j]);
      rm = fmaxf(rm, __shfl_xor(rm, 16, 64));
      rm = fmaxf(rm, __shfl_xor(rm, 32, 64));
      float mn = fmaxf(mst[m], rm);
      float corr = exp2f(mst[m] - mn);
      mst[m] = mn;
      float rs = 0.f;
#pragma unroll
      for (int kn = 0; kn < 4; ++kn) {
#pragma unroll
        for (int j = 0; j < 4; ++j) {
          float p = exp2f(sacc[kn][m][j] - mn);
          sacc[kn][m][j] = p;
          rs += p;
        }
        pw[m][kn][0] = cvtpk(sacc[kn][m][0], sacc[kn][m][1]);
        pw[m][kn][1] = cvtpk(sacc[kn][m][2], sacc[kn][m][3]);
      }
      rs += __shfl_xor(rs, 16, 64);
      rs += __shfl_xor(rs, 32, 64);
      lst[m] = lst[m] * corr + rs;
#pragma unroll
      for (int j = 0; j < 4; ++j) cbq[m][j] = __shfl(corr, l4 * 4 + j, 64);
#pragma unroll
      for (int n = 0; n < 4; ++n)
#pragma unroll
        for (int j = 0; j < 4; ++j) oacc[m][n][j] *= cbq[m][j];
    }

    __builtin_amdgcn_s_setprio(1);
#pragma unroll
    for (int kn = 0; kn < 4; ++kn) {
      bf16x4 vf[4];
#pragma unroll
      for (int n = 0; n < 4; ++n) {
        int bo = (n * 16 + l15) * 128 + (kn * 16 + l4 * 4) * 2;
        vf[n] = *(const bf16x4*)((const char*)Vt + swz(bo));
      }
#pragma unroll
      for (int m = 0; m < 2; ++m) {
        union { unsigned u[2]; bf16x4 h; } pk;
        pk.u[0] = pw[m][kn][0]; pk.u[1] = pw[m][kn][1];
#pragma unroll
        for (int n = 0; n < 4; ++n)
          oacc[m][n] = mfma16x16(pk.h, vf[n], oacc[m][n]);
      }
    }
    __builtin_amdgcn_s_setprio(0);
  }

  unsigned short* op = ow + base + (size_t)hf * 128 * kDk;
#pragma unroll
  for (int m = 0; m < 2; ++m) {
    float inv = 1.f / lst[m];
#pragma unroll
    for (int j = 0; j < 4; ++j) {
      float ib = __shfl(inv, l4 * 4 + j, 64);
      int srow = w * 32 + m * 16 + l4 * 4 + j;
#pragma unroll
      for (int n = 0; n < 4; ++n)
        op[(size_t)srow * 64 + n * 16 + l15] = f2bf(oacc[m][n][j] * ib);
    }
  }
}

}  // namespace

extern "C" void kernel_launch(void* const* d_in, const int* in_sizes, int n_in,
                              void* d_out, int out_size, void* d_ws, size_t ws_size,
                              hipStream_t stream) {
  const float* query = (const float*)d_in[0];
  const float* key   = (const float*)d_in[1];
  const float* value = (const float*)d_in[2];
  const float* Wq = (const float*)d_in[3];
  const float* bq = (const float*)d_in[4];
  const float* Wk = (const float*)d_in[5];
  const float* bk = (const float*)d_in[6];
  const float* Wv = (const float*)d_in[7];
  const float* bv = (const float*)d_in[8];
  const float* Wo = (const float*)d_in[9];
  const float* bo = (const float*)d_in[10];

  const float sQ = 0.125f * kLog2e;   // 1/sqrt(dk) * log2(e), folded into Q proj

  const size_t wsz = (size_t)kDm * kDm;          // 1M elems
  const size_t tsz = (size_t)kMr * kDm;          // 16M elems
  unsigned short* wsp = (unsigned short*)d_ws;
  unsigned short* wqb = wsp;                     // Wq|Wk|Wv|Wo contiguous
  unsigned short* wob = wqb + 3 * wsz;
  unsigned short* qws = wqb + 4 * wsz;
  unsigned short* kws = qws + tsz;
  unsigned short* vws = kws + tsz;
  unsigned short* aws = vws + tsz;

  const size_t need = (4 * wsz + 4 * tsz) * 2;   // 136 MB
  if (ws_size < need) return;

  cvt4<<<dim3(4096), dim3(256), 0, stream>>>(Wq, Wk, Wv, Wo, wqb);
  gemm_qkv8<<<dim3(768), dim3(512), 0, stream>>>(query, key, value, wqb,
                                                 bq, bk, bv, qws, sQ);
  attn_blkdiag<<<dim3(2048), 256, 0, stream>>>(qws, kws, vws, aws);
  gemm_o8<<<dim3(256), dim3(512), 0, stream>>>(aws, wob, bo, (float*)d_out);
}

// Round 11
// 244.749 us; speedup vs baseline: 1.2839x; 1.0033x over previous
//
#include <hip/hip_runtime.h>
#include <hip/hip_bf16.h>

// MemoryEfficientMultiheadAttention: chunked (block-diagonal) MHA.
// S=4096, B=4, D=1024, H=16, dk=64, CHUNK=256.
// cvt(weights only) -> fused QKV GEMM (8-phase 256x256, A = fp32 inputs with
// fused bf16 convert, 2-deep A-reg pipeline) -> flash attn (swapped QK^T,
// P-in-reg PV) -> out proj (8-phase 256x256, fp32 epilogue).

namespace {

constexpr int kSeq = 4096, kB = 4, kDm = 1024, kNh = 16, kDk = 64, kChk = 256;
constexpr int kMr = kSeq * kB;       // 16384 GEMM rows
constexpr float kLog2e = 1.44269504088896340736f;

typedef __attribute__((ext_vector_type(8))) short bf16x8;
typedef __attribute__((ext_vector_type(4))) short bf16x4;
typedef __attribute__((ext_vector_type(4))) float f32x4;
typedef __attribute__((ext_vector_type(8))) unsigned short u16x8;
typedef __attribute__((ext_vector_type(4))) unsigned short u16x4;
typedef __attribute__((ext_vector_type(4))) unsigned u32x4;

#define AS1 __attribute__((address_space(1)))
#define AS3 __attribute__((address_space(3)))

__device__ __forceinline__ unsigned short f2bf(float x) {
  union { float f; unsigned u; } v; v.f = x;
  unsigned r = v.u + 0x7fffu + ((v.u >> 16) & 1u);   // RNE
  return (unsigned short)(r >> 16);
}
// HW packed f32->bf16 (RNE): D[15:0]=bf16(lo), D[31:16]=bf16(hi).
__device__ __forceinline__ unsigned cvtpk(float lo, float hi) {
  unsigned r;
  asm("v_cvt_pk_bf16_f32 %0, %1, %2" : "=v"(r) : "v"(lo), "v"(hi));
  return r;
}
// XOR swizzle for 128B-row-stride LDS tiles: xor byte bits 4-6 with row&7.
__device__ __forceinline__ int swz(int bo) { return bo ^ ((bo >> 3) & 0x70); }

__device__ __forceinline__ f32x4 mfma16x16(bf16x4 a, bf16x4 b, f32x4 c) {
#if __has_builtin(__builtin_amdgcn_mfma_f32_16x16x16bf16_1k)
  return __builtin_amdgcn_mfma_f32_16x16x16bf16_1k(a, b, c, 0, 0, 0);
#else
  asm volatile("v_mfma_f32_16x16x16_bf16 %0, %1, %2, %0\n\ts_nop 4"
               : "+v"(c) : "v"(a), "v"(b));
  return c;
#endif
}

// All four 1024x1024 weights -> bf16, dst contiguous (Wq|Wk|Wv|Wo).
__global__ __launch_bounds__(256) void cvt4(const float* __restrict__ s0,
                                            const float* __restrict__ s1,
                                            const float* __restrict__ s2,
                                            const float* __restrict__ s3,
                                            unsigned short* __restrict__ dst) {
  int i = blockIdx.x * 256 + threadIdx.x;          // 0 .. 4*2^18-1
  int t = i >> 18;
  int j = i & 0x3ffff;
  const float* s = (t == 0) ? s0 : (t == 1) ? s1 : (t == 2) ? s2 : s3;
  f32x4 v = *(const f32x4*)(s + (size_t)j * 4);
  u16x4 o;
  o[0] = f2bf(v[0]); o[1] = f2bf(v[1]); o[2] = f2bf(v[2]); o[3] = f2bf(v[3]);
  *(u16x4*)(dst + (size_t)i * 4) = o;
}

// ---- Fused QKV projection, 8-phase 256x256 template (T3+T4+T2+T14) ----
// A = ORIGINAL fp32 inputs with fused bf16 convert. 2-deep A-reg pipeline:
// at tile T, p0/p1 load A(T+2) into reg-set (T&1); p3 writes A(T+1) from set
// ((T+1)&1), loaded a full K-tile earlier -> its auto vmcnt-wait is free.
// Explicit gate at p3: vmcnt(12) (A(T+2) 8 + B(T+2) 4 stay in flight) drains
// B(T+1) before tile T+1 reads it. LDS content invariant: chunk(row,c) holds
// global chunk c^(row&7) -> the swizzled ds_reads are unchanged.
__global__ __launch_bounds__(512, 2) void gemm_qkv8(
    const float* __restrict__ qf, const float* __restrict__ kf,
    const float* __restrict__ vf, const unsigned short* __restrict__ Wcat,
    const float* __restrict__ bq, const float* __restrict__ bk,
    const float* __restrict__ bv, unsigned short* __restrict__ dst, float sQ) {
  constexpr int K = kDm, nkt = K / 64;   // 16
  __shared__ unsigned short sh[65536];   // 128 KB: A slots [0,32768), B [32768,65536)
  const int tid = (int)threadIdx.x;      // 0..511
  const int l = tid & 63;
  const int l15 = l & 15, l4 = l >> 4, l7 = l15 & 7;
  const int wid = tid >> 6, wm = wid >> 2, wn = wid & 3, wn1 = wn & 1;
  const int bid = (int)blockIdx.x;
  const int xcd = bid & 7, idx = bid >> 3;          // idx 0..95
  const int rbi = xcd * 8 + (idx & 7);              // 0..63
  const int cbi = idx >> 3;                         // 0..11
  const int mat = cbi >> 2, ccol = (cbi & 3) * 256;
  const float* bp = (mat == 0) ? bq : (mat == 1) ? bk : bv;
  const float scale = (mat == 0) ? sQ : 1.0f;
  const float* Ain = (mat == 0) ? qf : (mat == 1) ? kf : vf;
  unsigned short* out = dst + (size_t)mat * kMr * kDm;

  // A staging: thread owns row arow, bf16-chunks (ac2, ac2+1) of each half.
  const int arow = tid >> 2;                        // 0..127
  const int ac2 = (tid & 3) * 2;                    // 0,2,4,6
  const float* gA = Ain + (size_t)(rbi * 256 + arow) * K + ac2 * 8;
  const int awc0 = (ac2 ^ (arow & 7)) * 8;          // write chunk-XOR (shorts)
  const int awc1 = ((ac2 + 1) ^ (arow & 7)) * 8;
  // B staging: gload_lds, source pre-swizzled.
  const int srow = tid >> 3;
  const int g16 = (tid & 7) ^ (srow & 7);
  const unsigned short* gB = Wcat + (size_t)(cbi * 256 + srow) * K + g16 * 8;
  const int ldsbase = (tid & ~63) * 8;

  auto stageB = [&](int T, int h) {
    const unsigned short* s = gB + (size_t)h * (128 * K) + T * 64;
    unsigned short* d = sh + 32768 + ((T & 1) * 2 + h) * 8192 + ldsbase;
    __builtin_amdgcn_global_load_lds((const AS1 unsigned int*)s, (AS3 unsigned int*)d, 16, 0, 0);
    __builtin_amdgcn_global_load_lds((const AS1 unsigned int*)(s + 64 * K),
                                     (AS3 unsigned int*)(d + 4096), 16, 0, 0);
  };
  auto loadA = [&](f32x4* r, int T, int h) {
    const float* s = gA + (size_t)h * (128 * K) + T * 64;
    r[0] = *(const f32x4*)s;
    r[1] = *(const f32x4*)(s + 4);
    r[2] = *(const f32x4*)(s + 8);
    r[3] = *(const f32x4*)(s + 12);
  };
  auto writeA = [&](const f32x4* r, int T, int h) {
    unsigned short* d = sh + ((T & 1) * 2 + h) * 8192 + arow * 64;
    u32x4 w0 = {cvtpk(r[0][0], r[0][1]), cvtpk(r[0][2], r[0][3]),
                cvtpk(r[1][0], r[1][1]), cvtpk(r[1][2], r[1][3])};
    u32x4 w1 = {cvtpk(r[2][0], r[2][1]), cvtpk(r[2][2], r[2][3]),
                cvtpk(r[3][0], r[3][1]), cvtpk(r[3][2], r[3][3])};
    *(u32x4*)(d + awc0) = w0;
    *(u32x4*)(d + awc1) = w1;
  };

  f32x4 acc[8][4] = {};
  f32x4 a0[2][4], a1[2][4];   // 2 reg-sets x 2 halves (all static-indexed)
  bf16x8 bfr[4];

  // Prologue: A(0)->set0, A(1)->set1, B(0), B(1) issued; write A(0);
  // vmcnt(4) leaves B(1) in flight (B(0)+set1 drained).
  loadA(a0[0], 0, 0); loadA(a0[1], 0, 1);
  loadA(a1[0], 1, 0); loadA(a1[1], 1, 1);
  stageB(0, 0); stageB(0, 1);
  stageB(1, 0); stageB(1, 1);
  writeA(a0[0], 0, 0); writeA(a0[1], 0, 1);
  asm volatile("s_waitcnt lgkmcnt(0)" ::: "memory");
  asm volatile("s_waitcnt vmcnt(4)" ::: "memory");
  __builtin_amdgcn_s_barrier();

  for (int it = 0; it < nkt / 2; ++it) {
#pragma unroll
    for (int tt = 0; tt < 2; ++tt) {
      const int T = 2 * it + tt;
      const unsigned short* Asl = sh + (tt * 2 + wm) * 8192;
      const unsigned short* Bsl = sh + 32768 + (tt * 2 + (wn >> 1)) * 8192;
#pragma unroll
      for (int p = 0; p < 4; ++p) {
        const int kk = p >> 1, mfh = p & 1;
        bf16x8 af[4];
        const int sc = ((kk * 4 + l4) ^ l7) * 8;
        if (mfh == 0) {
#pragma unroll
          for (int nf = 0; nf < 4; ++nf)
            bfr[nf] = *(const bf16x8*)&Bsl[(wn1 * 64 + nf * 16 + l15) * 64 + sc];
        }
#pragma unroll
        for (int i = 0; i < 4; ++i)
          af[i] = *(const bf16x8*)&Asl[(mfh * 64 + i * 16 + l15) * 64 + sc];
        // A(T+2) loads into set (T&1)=tt (issue-early, full tile of latency)
        if (p == 0 && T + 2 < nkt) {
          loadA(tt == 0 ? a0[0] : a1[0], T + 2, 0);
          __builtin_amdgcn_sched_barrier(0);
        }
        if (p == 1 && T + 2 < nkt) {
          loadA(tt == 0 ? a0[1] : a1[1], T + 2, 1);
          __builtin_amdgcn_sched_barrier(0);
        }
        if (p == 3) {
          if (T + 2 < nkt) { stageB(T + 2, 0); stageB(T + 2, 1); }
          if (T + 1 < nkt) {   // set ((T+1)&1): loaded a full tile ago
            writeA(tt == 0 ? a1[0] : a0[0], T + 1, 0);
            writeA(tt == 0 ? a1[1] : a0[1], T + 1, 1);
          }
        }
        __builtin_amdgcn_s_barrier();
        __builtin_amdgcn_s_setprio(1);
#pragma unroll
        for (int i = 0; i < 4; ++i)
#pragma unroll
          for (int nf = 0; nf < 4; ++nf)
            acc[mfh * 4 + i][nf] =
                __builtin_amdgcn_mfma_f32_16x16x32_bf16(af[i], bfr[nf], acc[mfh * 4 + i][nf], 0, 0, 0);
        __builtin_amdgcn_s_setprio(0);
        if (p == 3) {
          asm volatile("s_waitcnt lgkmcnt(0)" ::: "memory");  // publish A writes
          if (T + 1 < nkt) {   // counted gate: drain B(T+1) only
            if (T + 2 < nkt) asm volatile("s_waitcnt vmcnt(12)" ::: "memory");
            else             asm volatile("s_waitcnt vmcnt(0)" ::: "memory");
          }
        }
        __builtin_amdgcn_s_barrier();
      }
    }
  }

  // Epilogue: restage 256x256 C into LDS (store-order + XOR swz), then
  // coalesced head-major stores.
#pragma unroll
  for (int mf = 0; mf < 8; ++mf)
#pragma unroll
    for (int nf = 0; nf < 4; ++nf) {
      int col = wn * 64 + nf * 16 + l15;            // tile-local col 0..255
      float bvv = bp[ccol + col];
      int grpc = col >> 6;
      int c16 = (col & 63) >> 3, pos = col & 7;
      unsigned p01 = cvtpk((acc[mf][nf][0] + bvv) * scale, (acc[mf][nf][1] + bvv) * scale);
      unsigned p23 = cvtpk((acc[mf][nf][2] + bvv) * scale, (acc[mf][nf][3] + bvv) * scale);
      unsigned short ev[4] = {(unsigned short)p01, (unsigned short)(p01 >> 16),
                              (unsigned short)p23, (unsigned short)(p23 >> 16)};
#pragma unroll
      for (int j = 0; j < 4; ++j) {
        int tl = wm * 128 + mf * 16 + l4 * 4 + j;   // tile-local row 0..255
        int grp = (tl & 3) * 4 + grpc;
        int u = (tl >> 2) * 8 + c16;
        int byte = (grp * 8192 + u * 16 + pos * 2) ^ (((u >> 3) & 7) << 4);
        *(unsigned short*)((char*)sh + byte) = ev[j];
      }
    }
  __syncthreads();
  {
    int inner = tid & 31, grp = tid >> 5;           // grp = b2*4 + hl
    int b2 = grp >> 2, hl = grp & 3;
    int h = (cbi & 3) * 4 + hl;
    unsigned short* po = out + ((size_t)(b2 * kNh + h) * kSeq + rbi * 64) * kDk;
#pragma unroll
    for (int i = 0; i < 16; ++i) {
      int u = i * 32 + inner;
      int byte = (grp * 8192 + u * 16) ^ (((u >> 3) & 7) << 4);
      u16x8 v = *(const u16x8*)((const char*)sh + byte);
      *(u16x8*)(po + u * 8) = v;
    }
  }
}

// ---- Output projection, 8-phase 256x256 template ----
// C[M,N] fp32 = A(head-major bf16) @ Wo^T + bo. 256 blocks = 1/CU.
__global__ __launch_bounds__(512, 2) void gemm_o8(const unsigned short* __restrict__ Aw,
                                                  const unsigned short* __restrict__ Bw,
                                                  const float* __restrict__ bias,
                                                  float* __restrict__ Cp) {
  constexpr int K = kDm, nkt = K / 64;   // 16
  __shared__ unsigned short sh[65536];
  const int tid = (int)threadIdx.x;
  const int l = tid & 63;
  const int l15 = l & 15, l4 = l >> 4, l7 = l15 & 7;
  const int wid = tid >> 6, wm = wid >> 2, wn = wid & 3, wn1 = wn & 1;
  const int bid = (int)blockIdx.x;
  const int xcd = bid & 7, idx = bid >> 3;          // idx 0..31
  const int rbi = xcd * 8 + (idx & 7);              // 0..63
  const int cbi = idx >> 3;                         // 0..3
  const int rb = rbi * 256, cb = cbi * 256;

  const int srow = tid >> 3;
  const int g16 = (tid & 7) ^ (srow & 7);
  size_t abase[2][2];
#pragma unroll
  for (int h = 0; h < 2; ++h)
#pragma unroll
    for (int i = 0; i < 2; ++i) {
      int t = rb + h * 128 + srow + 64 * i;
      abase[h][i] = ((size_t)((t & 3) * kNh) * kSeq + (t >> 2)) * kDk + g16 * 8;
    }
  const unsigned short* gB = Bw + (size_t)(cb + srow) * K + g16 * 8;
  const int ldsbase = (tid & ~63) * 8;

  auto stageA = [&](int T, int h) {
    unsigned short* d = sh + ((T & 1) * 2 + h) * 8192 + ldsbase;
    size_t ko = (size_t)T * ((size_t)kSeq * kDk);   // head T
    __builtin_amdgcn_global_load_lds((const AS1 unsigned int*)(Aw + abase[h][0] + ko),
                                     (AS3 unsigned int*)d, 16, 0, 0);
    __builtin_amdgcn_global_load_lds((const AS1 unsigned int*)(Aw + abase[h][1] + ko),
                                     (AS3 unsigned int*)(d + 4096), 16, 0, 0);
  };
  auto stageB = [&](int T, int h) {
    const unsigned short* s = gB + (size_t)h * (128 * K) + T * 64;
    unsigned short* d = sh + 32768 + ((T & 1) * 2 + h) * 8192 + ldsbase;
    __builtin_amdgcn_global_load_lds((const AS1 unsigned int*)s, (AS3 unsigned int*)d, 16, 0, 0);
    __builtin_amdgcn_global_load_lds((const AS1 unsigned int*)(s + 64 * K),
                                     (AS3 unsigned int*)(d + 4096), 16, 0, 0);
  };

  f32x4 acc[8][4] = {};
  bf16x8 bfr[4];

  stageB(0, 0); stageB(0, 1);
  stageA(0, 0); stageA(0, 1);
  stageB(1, 0); stageB(1, 1);
  asm volatile("s_waitcnt vmcnt(4)" ::: "memory");
  __builtin_amdgcn_s_barrier();

  for (int it = 0; it < nkt / 2; ++it) {
#pragma unroll
    for (int tt = 0; tt < 2; ++tt) {
      const int T = 2 * it + tt;
      const unsigned short* Asl = sh + (tt * 2 + wm) * 8192;
      const unsigned short* Bsl = sh + 32768 + (tt * 2 + (wn >> 1)) * 8192;
#pragma unroll
      for (int p = 0; p < 4; ++p) {
        const int kk = p >> 1, mfh = p & 1;
        bf16x8 af[4];
        const int sc = ((kk * 4 + l4) ^ l7) * 8;
        if (mfh == 0) {
#pragma unroll
          for (int nf = 0; nf < 4; ++nf)
            bfr[nf] = *(const bf16x8*)&Bsl[(wn1 * 64 + nf * 16 + l15) * 64 + sc];
        }
#pragma unroll
        for (int i = 0; i < 4; ++i)
          af[i] = *(const bf16x8*)&Asl[(mfh * 64 + i * 16 + l15) * 64 + sc];
        if (p == 0 && T + 1 < nkt) stageA(T + 1, 0);
        if (p == 1 && T + 1 < nkt) stageA(T + 1, 1);
        if (p == 3 && T + 2 < nkt) { stageB(T + 2, 0); stageB(T + 2, 1); }
        __builtin_amdgcn_s_barrier();
        __builtin_amdgcn_s_setprio(1);
#pragma unroll
        for (int i = 0; i < 4; ++i)
#pragma unroll
          for (int nf = 0; nf < 4; ++nf)
            acc[mfh * 4 + i][nf] =
                __builtin_amdgcn_mfma_f32_16x16x32_bf16(af[i], bfr[nf], acc[mfh * 4 + i][nf], 0, 0, 0);
        __builtin_amdgcn_s_setprio(0);
        if (p == 3 && T + 1 < nkt) {
          if (T + 2 < nkt) asm volatile("s_waitcnt vmcnt(4)" ::: "memory");
          else             asm volatile("s_waitcnt vmcnt(0)" ::: "memory");
        }
        __builtin_amdgcn_s_barrier();
      }
    }
  }

#pragma unroll
  for (int nf = 0; nf < 4; ++nf) {
    int col = cb + wn * 64 + nf * 16 + l15;
    float bvv = bias[col];
#pragma unroll
    for (int mf = 0; mf < 8; ++mf) {
      int row0 = rb + wm * 128 + mf * 16 + l4 * 4;
#pragma unroll
      for (int j = 0; j < 4; ++j)
        Cp[(size_t)(row0 + j) * kDm + col] = acc[mf][nf][j] + bvv;
    }
  }
}

// Block-diagonal flash attention, head-major (B*H, S, dk) in/out.
__global__ __launch_bounds__(256) void attn_blkdiag(const unsigned short* __restrict__ qw,
                                                    const unsigned short* __restrict__ kw,
                                                    const unsigned short* __restrict__ vw,
                                                    unsigned short* __restrict__ ow) {
  __shared__ unsigned short Kl[64 * 64];       // [kv_row][d]   (swizzled)
  __shared__ unsigned short Vt[64 * 64];       // [d][kv_row]   (transposed, swizzled)
  const int tid = (int)threadIdx.x;
  const int w = tid >> 6, l = tid & 63;
  const int l15 = l & 15, l4 = l >> 4;
  const int bid0 = (int)blockIdx.x;
  const int bid = (bid0 & 7) * 256 + (bid0 >> 3);   // XCD swizzle, 2048 % 8 == 0
  const int hf = bid & 1, c = (bid >> 1) & 15, bh = bid >> 5;
  const size_t base = ((size_t)bh * kSeq + c * kChk) * kDk;
  const unsigned short* qp = qw + base + (size_t)hf * 128 * kDk;
  const unsigned short* kp = kw + base;
  const unsigned short* vp = vw + base;

  bf16x8 q[2][2];
#pragma unroll
  for (int m = 0; m < 2; ++m)
#pragma unroll
    for (int kk = 0; kk < 2; ++kk)
      q[m][kk] = *(const bf16x8*)(qp + (w * 32 + m * 16 + l15) * 64 + kk * 32 + l4 * 8);

  float mst[2] = {-1e30f, -1e30f}, lst[2] = {0.f, 0.f};
  f32x4 oacc[2][4] = {};

  const int r = tid >> 2, c0 = (tid & 3) * 16;
  u16x8 kr0, kr1, vr0, vr1;
  {
    const unsigned short* kt = kp + tid * 16;
    kr0 = *(const u16x8*)kt; kr1 = *(const u16x8*)(kt + 8);
    const unsigned short* vt = vp + tid * 16;
    vr0 = *(const u16x8*)vt; vr1 = *(const u16x8*)(vt + 8);
  }

  for (int kb = 0; kb < 4; ++kb) {
    __syncthreads();
    {
      int bo = r * 128 + c0 * 2;
      *(u16x8*)((char*)Kl + swz(bo)) = kr0;
      *(u16x8*)((char*)Kl + swz(bo + 16)) = kr1;
#pragma unroll
      for (int j = 0; j < 8; ++j) {
        *(unsigned short*)((char*)Vt + swz((c0 + j) * 128 + r * 2)) = vr0[j];
        *(unsigned short*)((char*)Vt + swz((c0 + 8 + j) * 128 + r * 2)) = vr1[j];
      }
    }
    __syncthreads();
    if (kb < 3) {
      const unsigned short* kt = kp + (kb + 1) * (64 * kDk) + tid * 16;
      kr0 = *(const u16x8*)kt; kr1 = *(const u16x8*)(kt + 8);
      const unsigned short* vt = vp + (kb + 1) * (64 * kDk) + tid * 16;
      vr0 = *(const u16x8*)vt; vr1 = *(const u16x8*)(vt + 8);
    }

    f32x4 sacc[4][2] = {};
    __builtin_amdgcn_s_setprio(1);
#pragma unroll
    for (int kk = 0; kk < 2; ++kk) {
      bf16x8 kf[4];
#pragma unroll
      for (int kn = 0; kn < 4; ++kn) {
        int bo = (kn * 16 + l15) * 128 + (kk * 32 + l4 * 8) * 2;
        kf[kn] = *(const bf16x8*)((const char*)Kl + swz(bo));
      }
#pragma unroll
      for (int kn = 0; kn < 4; ++kn)
#pragma unroll
        for (int m = 0; m < 2; ++m)
          sacc[kn][m] = __builtin_amdgcn_mfma_f32_16x16x32_bf16(kf[kn], q[m][kk], sacc[kn][m], 0, 0, 0);
    }
    __builtin_amdgcn_s_setprio(0);

    unsigned pw[2][4][2];
    float cbq[2][4];
#pragma unroll
    for (int m = 0; m < 2; ++m) {
      float rm = -1e30f;
#pragma unroll
      for (int kn = 0; kn < 4; ++kn)
#pragma unroll
        for (int j = 0; j < 4; ++j) rm = fmaxf(rm, sacc[kn][m][j]);
      rm = fmaxf(rm, __shfl_xor(rm, 16, 64));
      rm = fmaxf(rm, __shfl_xor(rm, 32, 64));
      float mn = fmaxf(mst[m], rm);
      float corr = exp2f(mst[m] - mn);
      mst[m] = mn;
      float rs = 0.f;
#pragma unroll
      for (int kn = 0; kn < 4; ++kn) {
#pragma unroll
        for (int j = 0; j < 4; ++j) {
          float p = exp2f(sacc[kn][m][j] - mn);
          sacc[kn][m][j] = p;
          rs += p;
        }
        pw[m][kn][0] = cvtpk(sacc[kn][m][0], sacc[kn][m][1]);
        pw[m][kn][1] = cvtpk(sacc[kn][m][2], sacc[kn][m][3]);
      }
      rs += __shfl_xor(rs, 16, 64);
      rs += __shfl_xor(rs, 32, 64);
      lst[m] = lst[m] * corr + rs;
#pragma unroll
      for (int j = 0; j < 4; ++j) cbq[m][j] = __shfl(corr, l4 * 4 + j, 64);
#pragma unroll
      for (int n = 0; n < 4; ++n)
#pragma unroll
        for (int j = 0; j < 4; ++j) oacc[m][n][j] *= cbq[m][j];
    }

    __builtin_amdgcn_s_setprio(1);
#pragma unroll
    for (int kn = 0; kn < 4; ++kn) {
      bf16x4 vf[4];
#pragma unroll
      for (int n = 0; n < 4; ++n) {
        int bo = (n * 16 + l15) * 128 + (kn * 16 + l4 * 4) * 2;
        vf[n] = *(const bf16x4*)((const char*)Vt + swz(bo));
      }
#pragma unroll
      for (int m = 0; m < 2; ++m) {
        union { unsigned u[2]; bf16x4 h; } pk;
        pk.u[0] = pw[m][kn][0]; pk.u[1] = pw[m][kn][1];
#pragma unroll
        for (int n = 0; n < 4; ++n)
          oacc[m][n] = mfma16x16(pk.h, vf[n], oacc[m][n]);
      }
    }
    __builtin_amdgcn_s_setprio(0);
  }

  unsigned short* op = ow + base + (size_t)hf * 128 * kDk;
#pragma unroll
  for (int m = 0; m < 2; ++m) {
    float inv = 1.f / lst[m];
#pragma unroll
    for (int j = 0; j < 4; ++j) {
      float ib = __shfl(inv, l4 * 4 + j, 64);
      int srow = w * 32 + m * 16 + l4 * 4 + j;
#pragma unroll
      for (int n = 0; n < 4; ++n)
        op[(size_t)srow * 64 + n * 16 + l15] = f2bf(oacc[m][n][j] * ib);
    }
  }
}

}  // namespace

extern "C" void kernel_launch(void* const* d_in, const int* in_sizes, int n_in,
                              void* d_out, int out_size, void* d_ws, size_t ws_size,
                              hipStream_t stream) {
  const float* query = (const float*)d_in[0];
  const float* key   = (const float*)d_in[1];
  const float* value = (const float*)d_in[2];
  const float* Wq = (const float*)d_in[3];
  const float* bq = (const float*)d_in[4];
  const float* Wk = (const float*)d_in[5];
  const float* bk = (const float*)d_in[6];
  const float* Wv = (const float*)d_in[7];
  const float* bv = (const float*)d_in[8];
  const float* Wo = (const float*)d_in[9];
  const float* bo = (const float*)d_in[10];

  const float sQ = 0.125f * kLog2e;   // 1/sqrt(dk) * log2(e), folded into Q proj

  const size_t wsz = (size_t)kDm * kDm;          // 1M elems
  const size_t tsz = (size_t)kMr * kDm;          // 16M elems
  unsigned short* wsp = (unsigned short*)d_ws;
  unsigned short* wqb = wsp;                     // Wq|Wk|Wv|Wo contiguous
  unsigned short* wob = wqb + 3 * wsz;
  unsigned short* qws = wqb + 4 * wsz;
  unsigned short* kws = qws + tsz;
  unsigned short* vws = kws + tsz;
  unsigned short* aws = vws + tsz;

  const size_t need = (4 * wsz + 4 * tsz) * 2;   // 136 MB
  if (ws_size < need) return;

  cvt4<<<dim3(4096), dim3(256), 0, stream>>>(Wq, Wk, Wv, Wo, wqb);
  gemm_qkv8<<<dim3(768), dim3(512), 0, stream>>>(query, key, value, wqb,
                                                 bq, bk, bv, qws, sQ);
  attn_blkdiag<<<dim3(2048), 256, 0, stream>>>(qws, kws, vws, aws);
  gemm_o8<<<dim3(256), dim3(512), 0, stream>>>(aws, wob, bo, (float*)d_out);
}